// Round 13
// baseline (191.538 us; speedup 1.0000x reference)
//
#include <hip/hip_runtime.h>
#include <hip/hip_bf16.h>

#define BATCHN 2
#define SEQL 1000
#define DMODEL 1024
#define DSTATE 128
#define HEADDIM 64
#define DINNER 2048
#define NHEADS 32
#define CONVDIM 2304   // DINNER + 2*DSTATE
#define NPROJ 4384     // 2*DINNER + 2*DSTATE + NHEADS
#define TOKENS 2000
#define MPAD 2048      // tokens padded to 128 multiple
#define NPAD1 4480     // NPROJ padded to 128 multiple
#define QC 64          // SSD chunk length
#define NCH 16         // chunks per sequence

typedef __bf16 bfx8 __attribute__((ext_vector_type(8)));
typedef float fx4 __attribute__((ext_vector_type(4)));
typedef unsigned short u16x8 __attribute__((ext_vector_type(8)));

__device__ __forceinline__ unsigned short f2bf(float f) {
    unsigned int u = __builtin_bit_cast(unsigned int, f);
    u += 0x7FFFu + ((u >> 16) & 1u);
    return (unsigned short)(u >> 16);
}
__device__ __forceinline__ float bf2f(unsigned short u) {
    return __builtin_bit_cast(float, ((unsigned int)u) << 16);
}

__device__ __forceinline__ void gload16(const void* g, void* l) {
    __builtin_amdgcn_global_load_lds(
        (const __attribute__((address_space(1))) void*)g,
        (__attribute__((address_space(3))) void*)l, 16, 0, 0);
}

// ---------------- fp32 -> bf16 conversion with zero padding ----------------
__global__ __launch_bounds__(256) void k_f2bf_pad(const float* __restrict__ src,
                                                  unsigned short* __restrict__ dst,
                                                  int n4src, int n4dst) {
    int i = blockIdx.x * 256 + threadIdx.x;
    if (i >= n4dst) return;
    ushort4 o = {0, 0, 0, 0};
    if (i < n4src) {
        float4 v = ((const float4*)src)[i];
        o.x = f2bf(v.x); o.y = f2bf(v.y); o.z = f2bf(v.z); o.w = f2bf(v.w);
    }
    ((ushort4*)dst)[i] = o;
}

// ---------------- dt head projection in fp32 (exp-sensitive path) ----------------
__global__ __launch_bounds__(256) void k_dt(const float* __restrict__ x,
                                            const float* __restrict__ win,
                                            const float* __restrict__ dt_bias,
                                            float* __restrict__ dtv) {
    __shared__ float sx[8][1024];
    int t = threadIdx.x;
    int tok0 = blockIdx.x * 8;
    for (int i = t; i < 8 * 256; i += 256) {
        int tok = i >> 8, k4 = i & 255;
        ((float4*)&sx[tok][0])[k4] = ((const float4*)(x + (size_t)(tok0 + tok) * DMODEL))[k4];
    }
    __syncthreads();
    int tl = t >> 5, h = t & 31;
    const float4* wr_ = (const float4*)(win + (size_t)(2 * DINNER + 2 * DSTATE + h) * DMODEL);
    const float4* xr = (const float4*)&sx[tl][0];
    float acc = 0.f;
    #pragma unroll 4
    for (int k = 0; k < 256; ++k) {
        float4 a = xr[k], b = wr_[k];
        acc += a.x * b.x + a.y * b.y + a.z * b.z + a.w * b.w;
    }
    float v = acc + dt_bias[h];
    dtv[(size_t)(tok0 + tl) * NHEADS + h] = fmaxf(v, 0.f) + log1pf(expf(-fabsf(v)));
}

// ---------------- bf16 NT GEMM: 128x128 tile, BK=64, dbuf-2, swizzled ----------
// C[M][N] = A[M][K] * B[N][K]^T over K-chunk [z*kc,(z+1)*kc); C += z*pstride.
// Identical structure to the proven BK=32 dbuf (stage-next -> compute -> sync),
// but BK=64: half the barriers, and the 8 staging loads get a full 32-MFMA
// compute phase (~700cyc) before the barrier's vmcnt(0) drain.
// Rows are 64 bf16 (128B); slot8 ^= (row&7) swizzle -> 2-way residual (free).
__global__ __launch_bounds__(256) void k_gemmk(const unsigned short* __restrict__ A,
                                               const unsigned short* __restrict__ B,
                                               float* __restrict__ C,
                                               int Mstore, int N, int K,
                                               int kc, size_t pstride) {
    __shared__ __attribute__((aligned(16))) unsigned short As[2][8192];  // 128 x 64
    __shared__ __attribute__((aligned(16))) unsigned short Bs[2][8192];
    int t = threadIdx.x;
    int lane = t & 63, wave = t >> 6;
    int wr = wave >> 1, wc = wave & 1;
    int m0 = blockIdx.y * 128, n0 = blockIdx.x * 128;
    int k0 = blockIdx.z * kc;
    int nk = kc / 64;
    // staging: load j (0..3) covers rows j*32 + (t>>3); slot = t&7;
    // source col pre-swizzled: (slot ^ (row&7))*8, row&7 == (t>>3)&7
    int scol = (((t & 7) ^ ((t >> 3) & 7)) * 8);
    const unsigned short* Ag = A + (size_t)(m0 + (t >> 3)) * K + k0 + scol;
    const unsigned short* Bg = B + (size_t)(n0 + (t >> 3)) * K + k0 + scol;
    int fr = lane & 15, ks = lane >> 4;
    fx4 acc[4][4] = {};

#define STAGEK(bi, s) do {                                              \
        int ko_ = (s) * 64;                                             \
        gload16(Ag + ko_, &As[bi][t * 8]);                              \
        gload16(Ag + (size_t)32 * K + ko_, &As[bi][2048 + t * 8]);      \
        gload16(Ag + (size_t)64 * K + ko_, &As[bi][4096 + t * 8]);      \
        gload16(Ag + (size_t)96 * K + ko_, &As[bi][6144 + t * 8]);      \
        gload16(Bg + ko_, &Bs[bi][t * 8]);                              \
        gload16(Bg + (size_t)32 * K + ko_, &Bs[bi][2048 + t * 8]);      \
        gload16(Bg + (size_t)64 * K + ko_, &Bs[bi][4096 + t * 8]);      \
        gload16(Bg + (size_t)96 * K + ko_, &Bs[bi][6144 + t * 8]);      \
    } while (0)

#define COMPUTEK(bi) do {                                               \
        _Pragma("unroll")                                               \
        for (int kh = 0; kh < 2; ++kh) {                                \
            bfx8 a_[4], b_[4];                                          \
            _Pragma("unroll")                                           \
            for (int m = 0; m < 4; ++m) {                               \
                int R = wr * 64 + m * 16 + fr;                          \
                a_[m] = *(const bfx8*)&As[bi][R * 64 + (((kh * 4 + ks) ^ (R & 7)) << 3)]; \
            }                                                           \
            _Pragma("unroll")                                           \
            for (int n = 0; n < 4; ++n) {                               \
                int R = wc * 64 + n * 16 + fr;                          \
                b_[n] = *(const bfx8*)&Bs[bi][R * 64 + (((kh * 4 + ks) ^ (R & 7)) << 3)]; \
            }                                                           \
            _Pragma("unroll")                                           \
            for (int m = 0; m < 4; ++m)                                 \
                _Pragma("unroll")                                       \
                for (int n = 0; n < 4; ++n)                             \
                    acc[m][n] = __builtin_amdgcn_mfma_f32_16x16x32_bf16(a_[m], b_[n], acc[m][n], 0, 0, 0); \
        }                                                               \
    } while (0)

    STAGEK(0, 0);
    __syncthreads();
    int cur = 0;
    for (int kt = 1; kt < nk; ++kt) {
        STAGEK(cur ^ 1, kt);     // issue next tile's 8 loads before compute
        COMPUTEK(cur);           // 32 MFMA + 16 ds_read cover the load latency
        __syncthreads();         // single drain per 64-K
        cur ^= 1;
    }
    COMPUTEK(cur);
#undef STAGEK
#undef COMPUTEK
    float* Cz = C + (size_t)blockIdx.z * pstride;
    #pragma unroll
    for (int m = 0; m < 4; ++m) {
        int rbase = m0 + wr * 64 + m * 16 + (lane >> 4) * 4;
        #pragma unroll
        for (int i = 0; i < 4; ++i) {
            int r = rbase + i;
            if (r < Mstore) {
                #pragma unroll
                for (int n = 0; n < 4; ++n) {
                    int c = n0 + wc * 64 + n * 16 + fr;
                    if (c < N) Cz[(size_t)r * N + c] = acc[m][n][i];
                }
            }
        }
    }
}

// ---------------- split-K reduce (2 planes): out = part[0] + part[1] ----------
__global__ __launch_bounds__(256) void k_red2(const float* __restrict__ part,
                                              float* __restrict__ out, int n4, size_t pstride4) {
    int i = blockIdx.x * 256 + threadIdx.x;
    if (i >= n4) return;
    const float4* p = (const float4*)part;
    float4 v0 = p[i];
    float4 v1 = p[i + pstride4];
    float4 o;
    o.x = v0.x + v1.x;
    o.y = v0.y + v1.y;
    o.z = v0.z + v1.z;
    o.w = v0.w + v1.w;
    ((float4*)out)[i] = o;
}

// ---------------- depthwise causal conv: 4 tokens/thread, register window -----
__global__ __launch_bounds__(256) void k_conv4(const float* __restrict__ zx,
                                               const float* __restrict__ cw,
                                               const float* __restrict__ cb,
                                               float* __restrict__ xbc) {
    int idx = blockIdx.x * 256 + threadIdx.x;
    if (idx >= (TOKENS / 4) * CONVDIM) return;
    int tg = idx / CONVDIM;
    int col = idx - tg * CONVDIM;
    int b = tg / 250;
    int l0 = (tg - b * 250) * 4;
    float in[7];
    #pragma unroll
    for (int j = 0; j < 7; ++j) {
        int lj = l0 - 3 + j;
        in[j] = (lj >= 0) ? zx[(size_t)(b * SEQL + lj) * NPROJ + DINNER + col] : 0.f;
    }
    float w0 = cw[col * 4], w1 = cw[col * 4 + 1], w2 = cw[col * 4 + 2], w3 = cw[col * 4 + 3];
    float bb = cb[col];
    #pragma unroll
    for (int i = 0; i < 4; ++i) {
        float a = bb + w0 * in[i] + w1 * in[i + 1] + w2 * in[i + 2] + w3 * in[i + 3];
        xbc[(size_t)(b * SEQL + l0 + i) * CONVDIM + col] = a / (1.f + expf(-a));
    }
}

// ================= SSD via MFMA, chunk = 64 =================
// Block index: h innermost so consecutive blocks share the (b,c) B/C panels
// (L2-hot). Sg/cumA keep the LOGICAL index ((b*NH+h)*NCH+c) for scan2v/yoff.
#define SCW 136
#define SWW 72
__global__ __launch_bounds__(256) void k_tile(const float* __restrict__ xbc,
                                              const float* __restrict__ dtv,
                                              const float* __restrict__ A_log,
                                              const float* __restrict__ Dp,
                                              float* __restrict__ ybuf,
                                              float* __restrict__ Sg,
                                              float* __restrict__ cumA) {
    __shared__ unsigned short sC[64 * SCW];
    __shared__ unsigned short sB[64 * SCW];   // reused as W [64*SWW] after G
    __shared__ unsigned short sBdT[128 * SWW];
    __shared__ unsigned short sXdT[64 * SWW];
    __shared__ unsigned short sXr[64 * SWW];
    __shared__ float sAcs[64];
    __shared__ float sdt[64];
    int bid = blockIdx.x;
    int h = bid & 31;
    int tmp = bid >> 5;
    int c = tmp & 15;
    int b = tmp >> 4;
    size_t lin = (size_t)((b * NHEADS + h) * NCH + c);   // logical Sg/cumA index
    int t = threadIdx.x;
    int lane = t & 63, wave = t >> 6;
    if (t < 64) {
        int tok = c * QC + t;
        float d = (tok < SEQL) ? dtv[(size_t)(b * SEQL + tok) * NHEADS + h] : 0.f;
        float A = -expf(A_log[h]);
        float v = A * d;
        #pragma unroll
        for (int off = 1; off < 64; off <<= 1) {
            float u = __shfl_up(v, off, 64);
            if (lane >= off) v += u;
        }
        sdt[t] = d;
        sAcs[t] = v;
        cumA[lin * 64 + t] = v;
    }
    __syncthreads();
    float Aend = sAcs[63];
    for (int i = t; i < 64 * 32; i += 256) {
        int l = i >> 5, n4 = (i & 31) * 4;
        int tok = c * QC + l;
        float4 cv = {0, 0, 0, 0}, bv = {0, 0, 0, 0};
        if (tok < SEQL) {
            const float* base = xbc + (size_t)(b * SEQL + tok) * CONVDIM;
            bv = *(const float4*)(base + DINNER + n4);
            cv = *(const float4*)(base + DINNER + DSTATE + n4);
        }
        float dec = expf(Aend - sAcs[l]);
        sC[l * SCW + n4 + 0] = f2bf(cv.x); sC[l * SCW + n4 + 1] = f2bf(cv.y);
        sC[l * SCW + n4 + 2] = f2bf(cv.z); sC[l * SCW + n4 + 3] = f2bf(cv.w);
        sB[l * SCW + n4 + 0] = f2bf(bv.x); sB[l * SCW + n4 + 1] = f2bf(bv.y);
        sB[l * SCW + n4 + 2] = f2bf(bv.z); sB[l * SCW + n4 + 3] = f2bf(bv.w);
        sBdT[(n4 + 0) * SWW + l] = f2bf(bv.x * dec);
        sBdT[(n4 + 1) * SWW + l] = f2bf(bv.y * dec);
        sBdT[(n4 + 2) * SWW + l] = f2bf(bv.z * dec);
        sBdT[(n4 + 3) * SWW + l] = f2bf(bv.w * dec);
    }
    for (int i = t; i < 64 * 16; i += 256) {
        int l = i >> 4, p4 = (i & 15) * 4;
        int tok = c * QC + l;
        float4 xv = {0, 0, 0, 0};
        if (tok < SEQL) xv = *(const float4*)(xbc + (size_t)(b * SEQL + tok) * CONVDIM + h * 64 + p4);
        float d = sdt[l];
        sXr[l * SWW + p4 + 0] = f2bf(xv.x); sXr[l * SWW + p4 + 1] = f2bf(xv.y);
        sXr[l * SWW + p4 + 2] = f2bf(xv.z); sXr[l * SWW + p4 + 3] = f2bf(xv.w);
        sXdT[(p4 + 0) * SWW + l] = f2bf(xv.x * d);
        sXdT[(p4 + 1) * SWW + l] = f2bf(xv.y * d);
        sXdT[(p4 + 2) * SWW + l] = f2bf(xv.z * d);
        sXdT[(p4 + 3) * SWW + l] = f2bf(xv.w * d);
    }
    __syncthreads();
    int fr = lane & 15, fk8 = (lane >> 4) * 8;
    int wr = wave >> 1, wc = wave & 1;
    fx4 g[2][2] = {};
    #pragma unroll
    for (int k = 0; k < 4; ++k) {
        bfx8 a0 = *(const bfx8*)&sC[(wr * 32 + fr) * SCW + k * 32 + fk8];
        bfx8 a1 = *(const bfx8*)&sC[(wr * 32 + 16 + fr) * SCW + k * 32 + fk8];
        bfx8 b0 = *(const bfx8*)&sB[(wc * 32 + fr) * SCW + k * 32 + fk8];
        bfx8 b1 = *(const bfx8*)&sB[(wc * 32 + 16 + fr) * SCW + k * 32 + fk8];
        g[0][0] = __builtin_amdgcn_mfma_f32_16x16x32_bf16(a0, b0, g[0][0], 0, 0, 0);
        g[0][1] = __builtin_amdgcn_mfma_f32_16x16x32_bf16(a0, b1, g[0][1], 0, 0, 0);
        g[1][0] = __builtin_amdgcn_mfma_f32_16x16x32_bf16(a1, b0, g[1][0], 0, 0, 0);
        g[1][1] = __builtin_amdgcn_mfma_f32_16x16x32_bf16(a1, b1, g[1][1], 0, 0, 0);
    }
    __syncthreads();
    int rb = wr * 32 + (lane >> 4) * 4;
    int cb = wc * 32 + fr;
    #pragma unroll
    for (int m = 0; m < 2; ++m)
        #pragma unroll
        for (int n = 0; n < 2; ++n)
            #pragma unroll
            for (int i = 0; i < 4; ++i) {
                int row = rb + m * 16 + i, col = cb + n * 16;
                float wv = (col <= row) ? g[m][n][i] * expf(sAcs[row] - sAcs[col]) : 0.f;
                sB[row * SWW + col] = f2bf(wv);
            }
    __syncthreads();
    fx4 yd[2][2] = {};
    fx4 sc[2][4] = {};
    #pragma unroll
    for (int k = 0; k < 2; ++k) {
        bfx8 aW0 = *(const bfx8*)&sB[(wr * 32 + fr) * SWW + k * 32 + fk8];
        bfx8 aW1 = *(const bfx8*)&sB[(wr * 32 + 16 + fr) * SWW + k * 32 + fk8];
        bfx8 bX0 = *(const bfx8*)&sXdT[(wc * 32 + fr) * SWW + k * 32 + fk8];
        bfx8 bX1 = *(const bfx8*)&sXdT[(wc * 32 + 16 + fr) * SWW + k * 32 + fk8];
        yd[0][0] = __builtin_amdgcn_mfma_f32_16x16x32_bf16(aW0, bX0, yd[0][0], 0, 0, 0);
        yd[0][1] = __builtin_amdgcn_mfma_f32_16x16x32_bf16(aW0, bX1, yd[0][1], 0, 0, 0);
        yd[1][0] = __builtin_amdgcn_mfma_f32_16x16x32_bf16(aW1, bX0, yd[1][0], 0, 0, 0);
        yd[1][1] = __builtin_amdgcn_mfma_f32_16x16x32_bf16(aW1, bX1, yd[1][1], 0, 0, 0);
        bfx8 aX0 = *(const bfx8*)&sXdT[(wr * 32 + fr) * SWW + k * 32 + fk8];
        bfx8 aX1 = *(const bfx8*)&sXdT[(wr * 32 + 16 + fr) * SWW + k * 32 + fk8];
        #pragma unroll
        for (int j = 0; j < 4; ++j) {
            bfx8 bB = *(const bfx8*)&sBdT[(wc * 64 + j * 16 + fr) * SWW + k * 32 + fk8];
            sc[0][j] = __builtin_amdgcn_mfma_f32_16x16x32_bf16(aX0, bB, sc[0][j], 0, 0, 0);
            sc[1][j] = __builtin_amdgcn_mfma_f32_16x16x32_bf16(aX1, bB, sc[1][j], 0, 0, 0);
        }
    }
    float Dh = Dp[h];
    #pragma unroll
    for (int m = 0; m < 2; ++m)
        #pragma unroll
        for (int i = 0; i < 4; ++i) {
            int row = rb + m * 16 + i;
            int tok = c * QC + row;
            if (tok < SEQL) {
                #pragma unroll
                for (int n = 0; n < 2; ++n) {
                    int col = cb + n * 16;
                    float xr = bf2f(sXr[row * SWW + col]);
                    ybuf[(size_t)(b * SEQL + tok) * DINNER + h * 64 + col] = yd[m][n][i] + Dh * xr;
                }
            }
        }
    #pragma unroll
    for (int m = 0; m < 2; ++m)
        #pragma unroll
        for (int i = 0; i < 4; ++i) {
            int p = rb + m * 16 + i;
            #pragma unroll
            for (int j = 0; j < 4; ++j) {
                int n = wc * 64 + j * 16 + fr;
                Sg[lin * 8192 + p * 128 + n] = sc[m][j][i];
            }
        }
}

__global__ __launch_bounds__(256) void k_scan2v(float* __restrict__ Sg,
                                                const float* __restrict__ cumA) {
    int bid = blockIdx.x;
    int bh = bid >> 5, sub = bid & 31;
    int e = sub * 256 + threadIdx.x;
    __shared__ float sT[NCH];
    if (threadIdx.x < NCH)
        sT[threadIdx.x] = cumA[((size_t)(bh * NCH) + threadIdx.x) * 64 + 63];
    __syncthreads();
    float S = 0.f;
    size_t base = (size_t)bh * NCH * 8192 + e;
    for (int g = 0; g < NCH; ++g) {
        size_t off = base + (size_t)g * 8192;
        float sg = Sg[off];
        Sg[off] = S;
        S = expf(sT[g]) * S + sg;
    }
}

__global__ __launch_bounds__(256) void k_yoff(const float* __restrict__ xbc,
                                              const float* __restrict__ Sg,
                                              const float* __restrict__ cumA,
                                              float* __restrict__ ybuf) {
    int bid = blockIdx.x;
    int h = bid & 31;
    int tmp = bid >> 5;
    int c = tmp & 15;
    int b = tmp >> 4;
    if (c == 0) return;
    size_t lin = (size_t)((b * NHEADS + h) * NCH + c);
    __shared__ unsigned short sC[64 * SCW];
    __shared__ unsigned short sS[64 * SCW];
    __shared__ float sE[64];
    int t = threadIdx.x;
    int lane = t & 63, wave = t >> 6;
    if (t < 64) sE[t] = expf(cumA[lin * 64 + t]);
    for (int i = t; i < 64 * 32; i += 256) {
        int l = i >> 5, n4 = (i & 31) * 4;
        int tok = c * QC + l;
        float4 cv = {0, 0, 0, 0};
        if (tok < SEQL)
            cv = *(const float4*)(xbc + (size_t)(b * SEQL + tok) * CONVDIM + DINNER + DSTATE + n4);
        sC[l * SCW + n4 + 0] = f2bf(cv.x); sC[l * SCW + n4 + 1] = f2bf(cv.y);
        sC[l * SCW + n4 + 2] = f2bf(cv.z); sC[l * SCW + n4 + 3] = f2bf(cv.w);
        float4 sv = *(const float4*)(Sg + lin * 8192 + l * 128 + n4);
        sS[l * SCW + n4 + 0] = f2bf(sv.x); sS[l * SCW + n4 + 1] = f2bf(sv.y);
        sS[l * SCW + n4 + 2] = f2bf(sv.z); sS[l * SCW + n4 + 3] = f2bf(sv.w);
    }
    __syncthreads();
    int fr = lane & 15, fk8 = (lane >> 4) * 8;
    int wr = wave >> 1, wc = wave & 1;
    fx4 yo[2][2] = {};
    #pragma unroll
    for (int k = 0; k < 4; ++k) {
        bfx8 a0 = *(const bfx8*)&sC[(wr * 32 + fr) * SCW + k * 32 + fk8];
        bfx8 a1 = *(const bfx8*)&sC[(wr * 32 + 16 + fr) * SCW + k * 32 + fk8];
        bfx8 b0 = *(const bfx8*)&sS[(wc * 32 + fr) * SCW + k * 32 + fk8];
        bfx8 b1 = *(const bfx8*)&sS[(wc * 32 + 16 + fr) * SCW + k * 32 + fk8];
        yo[0][0] = __builtin_amdgcn_mfma_f32_16x16x32_bf16(a0, b0, yo[0][0], 0, 0, 0);
        yo[0][1] = __builtin_amdgcn_mfma_f32_16x16x32_bf16(a0, b1, yo[0][1], 0, 0, 0);
        yo[1][0] = __builtin_amdgcn_mfma_f32_16x16x32_bf16(a1, b0, yo[1][0], 0, 0, 0);
        yo[1][1] = __builtin_amdgcn_mfma_f32_16x16x32_bf16(a1, b1, yo[1][1], 0, 0, 0);
    }
    int rb = wr * 32 + (lane >> 4) * 4;
    int cb = wc * 32 + fr;
    #pragma unroll
    for (int m = 0; m < 2; ++m)
        #pragma unroll
        for (int i = 0; i < 4; ++i) {
            int row = rb + m * 16 + i;
            int tok = c * QC + row;
            if (tok < SEQL) {
                float e = sE[row];
                #pragma unroll
                for (int n = 0; n < 2; ++n) {
                    int col = cb + n * 16;
                    size_t off = (size_t)(b * SEQL + tok) * DINNER + h * 64 + col;
                    ybuf[off] += yo[m][n][i] * e;
                }
            }
        }
}

// ---------------- gate (y * silu(z)) + RMSNorm + norm_w, output bf16 (padded) ----
__global__ __launch_bounds__(256) void k_norm(const float* __restrict__ ybuf,
                                              const float* __restrict__ zx,
                                              const float* __restrict__ normw,
                                              unsigned short* __restrict__ ynb) {
    int row = blockIdx.x;
    int t = threadIdx.x;
    if (row >= TOKENS) {
        #pragma unroll
        for (int j = 0; j < 8; ++j) ynb[(size_t)row * DINNER + t + j * 256] = 0;
        return;
    }
    float v[8];
    float ss = 0.f;
    #pragma unroll
    for (int j = 0; j < 8; ++j) {
        int col = t + j * 256;
        float y = ybuf[(size_t)row * DINNER + col];
        float z = zx[(size_t)row * NPROJ + col];
        y *= z / (1.f + expf(-z));
        v[j] = y;
        ss += y * y;
    }
    #pragma unroll
    for (int off = 32; off > 0; off >>= 1) ss += __shfl_down(ss, off, 64);
    __shared__ float red[4];
    int lane = t & 63, wv = t >> 6;
    if (lane == 0) red[wv] = ss;
    __syncthreads();
    float tot = red[0] + red[1] + red[2] + red[3];
    float r = rsqrtf(tot * (1.f / DINNER) + 1e-5f);
    #pragma unroll
    for (int j = 0; j < 8; ++j) {
        int col = t + j * 256;
        ynb[(size_t)row * DINNER + col] = f2bf(v[j] * r * normw[col]);
    }
}

extern "C" void kernel_launch(void* const* d_in, const int* in_sizes, int n_in,
                              void* d_out, int out_size, void* d_ws, size_t ws_size,
                              hipStream_t stream) {
    const float* x       = (const float*)d_in[0];
    const float* W_in    = (const float*)d_in[1];
    const float* conv_w  = (const float*)d_in[2];
    const float* conv_b  = (const float*)d_in[3];
    const float* dt_bias = (const float*)d_in[4];
    const float* A_log   = (const float*)d_in[5];
    const float* Dp      = (const float*)d_in[6];
    const float* norm_w  = (const float*)d_in[7];
    const float* W_out   = (const float*)d_in[8];
    float* out = (float*)d_out;

    char* w = (char*)d_ws;
    auto alloc = [&](size_t bytes) {
        char* p = w;
        w += (bytes + 255) & ~(size_t)255;
        return p;
    };
    unsigned short* xb    = (unsigned short*)alloc((size_t)MPAD * DMODEL * 2);
    unsigned short* winb  = (unsigned short*)alloc((size_t)NPAD1 * DMODEL * 2);
    unsigned short* woutb = (unsigned short*)alloc((size_t)DMODEL * DINNER * 2);
    float* zx   = (float*)alloc((size_t)TOKENS * NPROJ * 4);   // also split-K partials for GEMM2
    float* xbc  = (float*)alloc((size_t)TOKENS * CONVDIM * 4);
    float* dtv  = (float*)alloc((size_t)TOKENS * NHEADS * 4);
    float* yb   = (float*)alloc((size_t)TOKENS * DINNER * 4);
    unsigned short* ynb = (unsigned short*)alloc((size_t)MPAD * DINNER * 2);
    float* Sg   = (float*)alloc((size_t)BATCHN * NHEADS * NCH * HEADDIM * DSTATE * 4);
    float* cumA = (float*)alloc((size_t)BATCHN * NHEADS * NCH * 64 * 4);

    int n4;
    n4 = MPAD * DMODEL / 4;
    k_f2bf_pad<<<(n4 + 255) / 256, 256, 0, stream>>>(x, xb, TOKENS * DMODEL / 4, n4);
    n4 = NPAD1 * DMODEL / 4;
    k_f2bf_pad<<<(n4 + 255) / 256, 256, 0, stream>>>(W_in, winb, NPROJ * DMODEL / 4, n4);
    n4 = DMODEL * DINNER / 4;
    k_f2bf_pad<<<(n4 + 255) / 256, 256, 0, stream>>>(W_out, woutb, n4, n4);
    k_dt<<<TOKENS / 8, 256, 0, stream>>>(x, W_in, dt_bias, dtv);
    // GEMM1: zx[2000][4384] = xb[2048][1024] * winb[4480][1024]^T, BK=64, nk=16
    dim3 g1(NPAD1 / 128, MPAD / 128, 1);
    k_gemmk<<<g1, 256, 0, stream>>>(xb, winb, zx, TOKENS, NPROJ, DMODEL, DMODEL, 0);
    k_conv4<<<(TOKENS / 4) * CONVDIM / 256, 256, 0, stream>>>(zx, conv_w, conv_b, xbc);
    k_tile<<<BATCHN * NHEADS * NCH, 256, 0, stream>>>(xbc, dtv, A_log, Dp, yb, Sg, cumA);
    k_scan2v<<<BATCHN * NHEADS * 32, 256, 0, stream>>>(Sg, cumA);
    k_yoff<<<BATCHN * NHEADS * NCH, 256, 0, stream>>>(xbc, Sg, cumA, yb);
    k_norm<<<MPAD, 256, 0, stream>>>(yb, zx, norm_w, ynb);
    // GEMM2 split-K=2: grid 8x16x2 = 256 blocks, kc=1024 (nk=16); partials into zx
    size_t pstride = (size_t)MPAD * DMODEL;
    dim3 g2(DMODEL / 128, MPAD / 128, 2);
    k_gemmk<<<g2, 256, 0, stream>>>(ynb, woutb, zx, MPAD, DMODEL, DINNER, DINNER / 2, pstride);
    n4 = TOKENS * DMODEL / 4;
    k_red2<<<(n4 + 255) / 256, 256, 0, stream>>>(zx, out, n4, pstride / 4);
}

// Round 14
// 186.475 us; speedup vs baseline: 1.0271x; 1.0271x over previous
//
#include <hip/hip_runtime.h>
#include <hip/hip_bf16.h>

#define BATCHN 2
#define SEQL 1000
#define DMODEL 1024
#define DSTATE 128
#define HEADDIM 64
#define DINNER 2048
#define NHEADS 32
#define CONVDIM 2304   // DINNER + 2*DSTATE
#define NPROJ 4384     // 2*DINNER + 2*DSTATE + NHEADS
#define TOKENS 2000
#define MPAD 2048      // tokens padded to 128 multiple
#define NPAD1 4480     // NPROJ padded to 128 multiple
#define QC 64          // SSD chunk length
#define NCH 16         // chunks per sequence

typedef __bf16 bfx8 __attribute__((ext_vector_type(8)));
typedef float fx4 __attribute__((ext_vector_type(4)));
typedef unsigned short u16x8 __attribute__((ext_vector_type(8)));

__device__ __forceinline__ unsigned short f2bf(float f) {
    unsigned int u = __builtin_bit_cast(unsigned int, f);
    u += 0x7FFFu + ((u >> 16) & 1u);
    return (unsigned short)(u >> 16);
}
__device__ __forceinline__ float bf2f(unsigned short u) {
    return __builtin_bit_cast(float, ((unsigned int)u) << 16);
}

__device__ __forceinline__ void gload16(const void* g, void* l) {
    __builtin_amdgcn_global_load_lds(
        (const __attribute__((address_space(1))) void*)g,
        (__attribute__((address_space(3))) void*)l, 16, 0, 0);
}

// ---------------- fp32 -> bf16 conversion with zero padding ----------------
__global__ __launch_bounds__(256) void k_f2bf_pad(const float* __restrict__ src,
                                                  unsigned short* __restrict__ dst,
                                                  int n4src, int n4dst) {
    int i = blockIdx.x * 256 + threadIdx.x;
    if (i >= n4dst) return;
    ushort4 o = {0, 0, 0, 0};
    if (i < n4src) {
        float4 v = ((const float4*)src)[i];
        o.x = f2bf(v.x); o.y = f2bf(v.y); o.z = f2bf(v.z); o.w = f2bf(v.w);
    }
    ((ushort4*)dst)[i] = o;
}

// ---------------- dt head projection in fp32 (exp-sensitive path) ----------------
__global__ __launch_bounds__(256) void k_dt(const float* __restrict__ x,
                                            const float* __restrict__ win,
                                            const float* __restrict__ dt_bias,
                                            float* __restrict__ dtv) {
    __shared__ float sx[8][1024];
    int t = threadIdx.x;
    int tok0 = blockIdx.x * 8;
    for (int i = t; i < 8 * 256; i += 256) {
        int tok = i >> 8, k4 = i & 255;
        ((float4*)&sx[tok][0])[k4] = ((const float4*)(x + (size_t)(tok0 + tok) * DMODEL))[k4];
    }
    __syncthreads();
    int tl = t >> 5, h = t & 31;
    const float4* wr_ = (const float4*)(win + (size_t)(2 * DINNER + 2 * DSTATE + h) * DMODEL);
    const float4* xr = (const float4*)&sx[tl][0];
    float acc = 0.f;
    #pragma unroll 4
    for (int k = 0; k < 256; ++k) {
        float4 a = xr[k], b = wr_[k];
        acc += a.x * b.x + a.y * b.y + a.z * b.z + a.w * b.w;
    }
    float v = acc + dt_bias[h];
    dtv[(size_t)(tok0 + tl) * NHEADS + h] = fmaxf(v, 0.f) + log1pf(expf(-fabsf(v)));
}

// ---------------- bf16 NT GEMM: 128x128 tile, 256 thr, dbuf-2, swizzled -------
// (r10's proven-best GEMM: ~46us/19GF. 7 schedule variants tried; all worse.)
// C[M][N] = A[M][K] * B[N][K]^T over K-chunk [z*kc,(z+1)*kc); C += z*pstride.
__global__ __launch_bounds__(256) void k_gemmd(const unsigned short* __restrict__ A,
                                               const unsigned short* __restrict__ B,
                                               float* __restrict__ C,
                                               int Mstore, int N, int K,
                                               int kc, size_t pstride) {
    __shared__ __attribute__((aligned(16))) unsigned short As[2][4096];  // 128x32
    __shared__ __attribute__((aligned(16))) unsigned short Bs[2][4096];
    int t = threadIdx.x;
    int lane = t & 63, wave = t >> 6;
    int wr = wave >> 1, wc = wave & 1;
    int m0 = blockIdx.y * 128, n0 = blockIdx.x * 128;
    int k0 = blockIdx.z * kc;
    int swcol = (((t & 3) ^ ((t >> 3) & 3)) * 8);
    const unsigned short* Ag = A + (size_t)(m0 + (t >> 2)) * K + k0 + swcol;
    const unsigned short* Bg = B + (size_t)(n0 + (t >> 2)) * K + k0 + swcol;
    int fr = lane & 15, ks = lane >> 4;
    int sl = (ks ^ ((fr >> 1) & 3)) << 3;
    fx4 acc[4][4] = {};
    gload16(Ag, &As[0][t * 8]);
    gload16(Ag + (size_t)64 * K, &As[0][2048 + t * 8]);
    gload16(Bg, &Bs[0][t * 8]);
    gload16(Bg + (size_t)64 * K, &Bs[0][2048 + t * 8]);
    __syncthreads();
    int cur = 0;
    for (int kk = 32; kk < kc; kk += 32) {
        gload16(Ag + kk, &As[cur ^ 1][t * 8]);
        gload16(Ag + (size_t)64 * K + kk, &As[cur ^ 1][2048 + t * 8]);
        gload16(Bg + kk, &Bs[cur ^ 1][t * 8]);
        gload16(Bg + (size_t)64 * K + kk, &Bs[cur ^ 1][2048 + t * 8]);
        bfx8 a[4], b[4];
        #pragma unroll
        for (int m = 0; m < 4; ++m)
            a[m] = *(const bfx8*)&As[cur][(wr * 64 + m * 16 + fr) * 32 + sl];
        #pragma unroll
        for (int n = 0; n < 4; ++n)
            b[n] = *(const bfx8*)&Bs[cur][(wc * 64 + n * 16 + fr) * 32 + sl];
        #pragma unroll
        for (int m = 0; m < 4; ++m)
            #pragma unroll
            for (int n = 0; n < 4; ++n)
                acc[m][n] = __builtin_amdgcn_mfma_f32_16x16x32_bf16(a[m], b[n], acc[m][n], 0, 0, 0);
        __syncthreads();
        cur ^= 1;
    }
    {
        bfx8 a[4], b[4];
        #pragma unroll
        for (int m = 0; m < 4; ++m)
            a[m] = *(const bfx8*)&As[cur][(wr * 64 + m * 16 + fr) * 32 + sl];
        #pragma unroll
        for (int n = 0; n < 4; ++n)
            b[n] = *(const bfx8*)&Bs[cur][(wc * 64 + n * 16 + fr) * 32 + sl];
        #pragma unroll
        for (int m = 0; m < 4; ++m)
            #pragma unroll
            for (int n = 0; n < 4; ++n)
                acc[m][n] = __builtin_amdgcn_mfma_f32_16x16x32_bf16(a[m], b[n], acc[m][n], 0, 0, 0);
    }
    float* Cz = C + (size_t)blockIdx.z * pstride;
    #pragma unroll
    for (int m = 0; m < 4; ++m) {
        int rbase = m0 + wr * 64 + m * 16 + (lane >> 4) * 4;
        #pragma unroll
        for (int i = 0; i < 4; ++i) {
            int r = rbase + i;
            if (r < Mstore) {
                #pragma unroll
                for (int n = 0; n < 4; ++n) {
                    int c = n0 + wc * 64 + n * 16 + fr;
                    if (c < N) Cz[(size_t)r * N + c] = acc[m][n][i];
                }
            }
        }
    }
}

// ---------------- split-K reduce: out = sum_z part[z] (4 planes) -------------
__global__ __launch_bounds__(256) void k_red(const float* __restrict__ part,
                                             float* __restrict__ out, int n4, size_t pstride4) {
    int i = blockIdx.x * 256 + threadIdx.x;
    if (i >= n4) return;
    const float4* p = (const float4*)part;
    float4 v0 = p[i];
    float4 v1 = p[i + pstride4];
    float4 v2 = p[i + 2 * pstride4];
    float4 v3 = p[i + 3 * pstride4];
    float4 o;
    o.x = (v0.x + v1.x) + (v2.x + v3.x);
    o.y = (v0.y + v1.y) + (v2.y + v3.y);
    o.z = (v0.z + v1.z) + (v2.z + v3.z);
    o.w = (v0.w + v1.w) + (v2.w + v3.w);
    ((float4*)out)[i] = o;
}

// ---------------- depthwise causal conv: 4 tokens/thread, register window -----
__global__ __launch_bounds__(256) void k_conv4(const float* __restrict__ zx,
                                               const float* __restrict__ cw,
                                               const float* __restrict__ cb,
                                               float* __restrict__ xbc) {
    int idx = blockIdx.x * 256 + threadIdx.x;
    if (idx >= (TOKENS / 4) * CONVDIM) return;
    int tg = idx / CONVDIM;
    int col = idx - tg * CONVDIM;
    int b = tg / 250;
    int l0 = (tg - b * 250) * 4;
    float in[7];
    #pragma unroll
    for (int j = 0; j < 7; ++j) {
        int lj = l0 - 3 + j;
        in[j] = (lj >= 0) ? zx[(size_t)(b * SEQL + lj) * NPROJ + DINNER + col] : 0.f;
    }
    float w0 = cw[col * 4], w1 = cw[col * 4 + 1], w2 = cw[col * 4 + 2], w3 = cw[col * 4 + 3];
    float bb = cb[col];
    #pragma unroll
    for (int i = 0; i < 4; ++i) {
        float a = bb + w0 * in[i] + w1 * in[i + 1] + w2 * in[i + 2] + w3 * in[i + 3];
        xbc[(size_t)(b * SEQL + l0 + i) * CONVDIM + col] = a / (1.f + expf(-a));
    }
}

// ================= SSD via MFMA, chunk = 64 =================
// Block index: h innermost so consecutive blocks share the (b,c) B/C panels
// (L2-hot; worth ~12us vs h-outermost per r12/r13 remainder analysis).
// Sg/cumA keep the LOGICAL index ((b*NH+h)*NCH+c) for scan2v/yoff.
#define SCW 136
#define SWW 72
__global__ __launch_bounds__(256) void k_tile(const float* __restrict__ xbc,
                                              const float* __restrict__ dtv,
                                              const float* __restrict__ A_log,
                                              const float* __restrict__ Dp,
                                              float* __restrict__ ybuf,
                                              float* __restrict__ Sg,
                                              float* __restrict__ cumA) {
    __shared__ unsigned short sC[64 * SCW];
    __shared__ unsigned short sB[64 * SCW];   // reused as W [64*SWW] after G
    __shared__ unsigned short sBdT[128 * SWW];
    __shared__ unsigned short sXdT[64 * SWW];
    __shared__ unsigned short sXr[64 * SWW];
    __shared__ float sAcs[64];
    __shared__ float sdt[64];
    int bid = blockIdx.x;
    int h = bid & 31;
    int tmp = bid >> 5;
    int c = tmp & 15;
    int b = tmp >> 4;
    size_t lin = (size_t)((b * NHEADS + h) * NCH + c);   // logical Sg/cumA index
    int t = threadIdx.x;
    int lane = t & 63, wave = t >> 6;
    if (t < 64) {
        int tok = c * QC + t;
        float d = (tok < SEQL) ? dtv[(size_t)(b * SEQL + tok) * NHEADS + h] : 0.f;
        float A = -expf(A_log[h]);
        float v = A * d;
        #pragma unroll
        for (int off = 1; off < 64; off <<= 1) {
            float u = __shfl_up(v, off, 64);
            if (lane >= off) v += u;
        }
        sdt[t] = d;
        sAcs[t] = v;
        cumA[lin * 64 + t] = v;
    }
    __syncthreads();
    float Aend = sAcs[63];
    for (int i = t; i < 64 * 32; i += 256) {
        int l = i >> 5, n4 = (i & 31) * 4;
        int tok = c * QC + l;
        float4 cv = {0, 0, 0, 0}, bv = {0, 0, 0, 0};
        if (tok < SEQL) {
            const float* base = xbc + (size_t)(b * SEQL + tok) * CONVDIM;
            bv = *(const float4*)(base + DINNER + n4);
            cv = *(const float4*)(base + DINNER + DSTATE + n4);
        }
        float dec = expf(Aend - sAcs[l]);
        sC[l * SCW + n4 + 0] = f2bf(cv.x); sC[l * SCW + n4 + 1] = f2bf(cv.y);
        sC[l * SCW + n4 + 2] = f2bf(cv.z); sC[l * SCW + n4 + 3] = f2bf(cv.w);
        sB[l * SCW + n4 + 0] = f2bf(bv.x); sB[l * SCW + n4 + 1] = f2bf(bv.y);
        sB[l * SCW + n4 + 2] = f2bf(bv.z); sB[l * SCW + n4 + 3] = f2bf(bv.w);
        sBdT[(n4 + 0) * SWW + l] = f2bf(bv.x * dec);
        sBdT[(n4 + 1) * SWW + l] = f2bf(bv.y * dec);
        sBdT[(n4 + 2) * SWW + l] = f2bf(bv.z * dec);
        sBdT[(n4 + 3) * SWW + l] = f2bf(bv.w * dec);
    }
    for (int i = t; i < 64 * 16; i += 256) {
        int l = i >> 4, p4 = (i & 15) * 4;
        int tok = c * QC + l;
        float4 xv = {0, 0, 0, 0};
        if (tok < SEQL) xv = *(const float4*)(xbc + (size_t)(b * SEQL + tok) * CONVDIM + h * 64 + p4);
        float d = sdt[l];
        sXr[l * SWW + p4 + 0] = f2bf(xv.x); sXr[l * SWW + p4 + 1] = f2bf(xv.y);
        sXr[l * SWW + p4 + 2] = f2bf(xv.z); sXr[l * SWW + p4 + 3] = f2bf(xv.w);
        sXdT[(p4 + 0) * SWW + l] = f2bf(xv.x * d);
        sXdT[(p4 + 1) * SWW + l] = f2bf(xv.y * d);
        sXdT[(p4 + 2) * SWW + l] = f2bf(xv.z * d);
        sXdT[(p4 + 3) * SWW + l] = f2bf(xv.w * d);
    }
    __syncthreads();
    int fr = lane & 15, fk8 = (lane >> 4) * 8;
    int wr = wave >> 1, wc = wave & 1;
    fx4 g[2][2] = {};
    #pragma unroll
    for (int k = 0; k < 4; ++k) {
        bfx8 a0 = *(const bfx8*)&sC[(wr * 32 + fr) * SCW + k * 32 + fk8];
        bfx8 a1 = *(const bfx8*)&sC[(wr * 32 + 16 + fr) * SCW + k * 32 + fk8];
        bfx8 b0 = *(const bfx8*)&sB[(wc * 32 + fr) * SCW + k * 32 + fk8];
        bfx8 b1 = *(const bfx8*)&sB[(wc * 32 + 16 + fr) * SCW + k * 32 + fk8];
        g[0][0] = __builtin_amdgcn_mfma_f32_16x16x32_bf16(a0, b0, g[0][0], 0, 0, 0);
        g[0][1] = __builtin_amdgcn_mfma_f32_16x16x32_bf16(a0, b1, g[0][1], 0, 0, 0);
        g[1][0] = __builtin_amdgcn_mfma_f32_16x16x32_bf16(a1, b0, g[1][0], 0, 0, 0);
        g[1][1] = __builtin_amdgcn_mfma_f32_16x16x32_bf16(a1, b1, g[1][1], 0, 0, 0);
    }
    __syncthreads();
    int rb = wr * 32 + (lane >> 4) * 4;
    int cb = wc * 32 + fr;
    #pragma unroll
    for (int m = 0; m < 2; ++m)
        #pragma unroll
        for (int n = 0; n < 2; ++n)
            #pragma unroll
            for (int i = 0; i < 4; ++i) {
                int row = rb + m * 16 + i, col = cb + n * 16;
                float wv = (col <= row) ? g[m][n][i] * expf(sAcs[row] - sAcs[col]) : 0.f;
                sB[row * SWW + col] = f2bf(wv);
            }
    __syncthreads();
    fx4 yd[2][2] = {};
    fx4 sc[2][4] = {};
    #pragma unroll
    for (int k = 0; k < 2; ++k) {
        bfx8 aW0 = *(const bfx8*)&sB[(wr * 32 + fr) * SWW + k * 32 + fk8];
        bfx8 aW1 = *(const bfx8*)&sB[(wr * 32 + 16 + fr) * SWW + k * 32 + fk8];
        bfx8 bX0 = *(const bfx8*)&sXdT[(wc * 32 + fr) * SWW + k * 32 + fk8];
        bfx8 bX1 = *(const bfx8*)&sXdT[(wc * 32 + 16 + fr) * SWW + k * 32 + fk8];
        yd[0][0] = __builtin_amdgcn_mfma_f32_16x16x32_bf16(aW0, bX0, yd[0][0], 0, 0, 0);
        yd[0][1] = __builtin_amdgcn_mfma_f32_16x16x32_bf16(aW0, bX1, yd[0][1], 0, 0, 0);
        yd[1][0] = __builtin_amdgcn_mfma_f32_16x16x32_bf16(aW1, bX0, yd[1][0], 0, 0, 0);
        yd[1][1] = __builtin_amdgcn_mfma_f32_16x16x32_bf16(aW1, bX1, yd[1][1], 0, 0, 0);
        bfx8 aX0 = *(const bfx8*)&sXdT[(wr * 32 + fr) * SWW + k * 32 + fk8];
        bfx8 aX1 = *(const bfx8*)&sXdT[(wr * 32 + 16 + fr) * SWW + k * 32 + fk8];
        #pragma unroll
        for (int j = 0; j < 4; ++j) {
            bfx8 bB = *(const bfx8*)&sBdT[(wc * 64 + j * 16 + fr) * SWW + k * 32 + fk8];
            sc[0][j] = __builtin_amdgcn_mfma_f32_16x16x32_bf16(aX0, bB, sc[0][j], 0, 0, 0);
            sc[1][j] = __builtin_amdgcn_mfma_f32_16x16x32_bf16(aX1, bB, sc[1][j], 0, 0, 0);
        }
    }
    float Dh = Dp[h];
    #pragma unroll
    for (int m = 0; m < 2; ++m)
        #pragma unroll
        for (int i = 0; i < 4; ++i) {
            int row = rb + m * 16 + i;
            int tok = c * QC + row;
            if (tok < SEQL) {
                #pragma unroll
                for (int n = 0; n < 2; ++n) {
                    int col = cb + n * 16;
                    float xr = bf2f(sXr[row * SWW + col]);
                    ybuf[(size_t)(b * SEQL + tok) * DINNER + h * 64 + col] = yd[m][n][i] + Dh * xr;
                }
            }
        }
    #pragma unroll
    for (int m = 0; m < 2; ++m)
        #pragma unroll
        for (int i = 0; i < 4; ++i) {
            int p = rb + m * 16 + i;
            #pragma unroll
            for (int j = 0; j < 4; ++j) {
                int n = wc * 64 + j * 16 + fr;
                Sg[lin * 8192 + p * 128 + n] = sc[m][j][i];
            }
        }
}

__global__ __launch_bounds__(256) void k_scan2v(float* __restrict__ Sg,
                                                const float* __restrict__ cumA) {
    int bid = blockIdx.x;
    int bh = bid >> 5, sub = bid & 31;
    int e = sub * 256 + threadIdx.x;
    __shared__ float sT[NCH];
    if (threadIdx.x < NCH)
        sT[threadIdx.x] = cumA[((size_t)(bh * NCH) + threadIdx.x) * 64 + 63];
    __syncthreads();
    float S = 0.f;
    size_t base = (size_t)bh * NCH * 8192 + e;
    for (int g = 0; g < NCH; ++g) {
        size_t off = base + (size_t)g * 8192;
        float sg = Sg[off];
        Sg[off] = S;
        S = expf(sT[g]) * S + sg;
    }
}

__global__ __launch_bounds__(256) void k_yoff(const float* __restrict__ xbc,
                                              const float* __restrict__ Sg,
                                              const float* __restrict__ cumA,
                                              float* __restrict__ ybuf) {
    int bid = blockIdx.x;
    int h = bid & 31;
    int tmp = bid >> 5;
    int c = tmp & 15;
    int b = tmp >> 4;
    if (c == 0) return;
    size_t lin = (size_t)((b * NHEADS + h) * NCH + c);
    __shared__ unsigned short sC[64 * SCW];
    __shared__ unsigned short sS[64 * SCW];
    __shared__ float sE[64];
    int t = threadIdx.x;
    int lane = t & 63, wave = t >> 6;
    if (t < 64) sE[t] = expf(cumA[lin * 64 + t]);
    for (int i = t; i < 64 * 32; i += 256) {
        int l = i >> 5, n4 = (i & 31) * 4;
        int tok = c * QC + l;
        float4 cv = {0, 0, 0, 0};
        if (tok < SEQL)
            cv = *(const float4*)(xbc + (size_t)(b * SEQL + tok) * CONVDIM + DINNER + DSTATE + n4);
        sC[l * SCW + n4 + 0] = f2bf(cv.x); sC[l * SCW + n4 + 1] = f2bf(cv.y);
        sC[l * SCW + n4 + 2] = f2bf(cv.z); sC[l * SCW + n4 + 3] = f2bf(cv.w);
        float4 sv = *(const float4*)(Sg + lin * 8192 + l * 128 + n4);
        sS[l * SCW + n4 + 0] = f2bf(sv.x); sS[l * SCW + n4 + 1] = f2bf(sv.y);
        sS[l * SCW + n4 + 2] = f2bf(sv.z); sS[l * SCW + n4 + 3] = f2bf(sv.w);
    }
    __syncthreads();
    int fr = lane & 15, fk8 = (lane >> 4) * 8;
    int wr = wave >> 1, wc = wave & 1;
    fx4 yo[2][2] = {};
    #pragma unroll
    for (int k = 0; k < 4; ++k) {
        bfx8 a0 = *(const bfx8*)&sC[(wr * 32 + fr) * SCW + k * 32 + fk8];
        bfx8 a1 = *(const bfx8*)&sC[(wr * 32 + 16 + fr) * SCW + k * 32 + fk8];
        bfx8 b0 = *(const bfx8*)&sS[(wc * 32 + fr) * SCW + k * 32 + fk8];
        bfx8 b1 = *(const bfx8*)&sS[(wc * 32 + 16 + fr) * SCW + k * 32 + fk8];
        yo[0][0] = __builtin_amdgcn_mfma_f32_16x16x32_bf16(a0, b0, yo[0][0], 0, 0, 0);
        yo[0][1] = __builtin_amdgcn_mfma_f32_16x16x32_bf16(a0, b1, yo[0][1], 0, 0, 0);
        yo[1][0] = __builtin_amdgcn_mfma_f32_16x16x32_bf16(a1, b0, yo[1][0], 0, 0, 0);
        yo[1][1] = __builtin_amdgcn_mfma_f32_16x16x32_bf16(a1, b1, yo[1][1], 0, 0, 0);
    }
    int rb = wr * 32 + (lane >> 4) * 4;
    int cb = wc * 32 + fr;
    #pragma unroll
    for (int m = 0; m < 2; ++m)
        #pragma unroll
        for (int i = 0; i < 4; ++i) {
            int row = rb + m * 16 + i;
            int tok = c * QC + row;
            if (tok < SEQL) {
                float e = sE[row];
                #pragma unroll
                for (int n = 0; n < 2; ++n) {
                    int col = cb + n * 16;
                    size_t off = (size_t)(b * SEQL + tok) * DINNER + h * 64 + col;
                    ybuf[off] += yo[m][n][i] * e;
                }
            }
        }
}

// ---------------- gate (y * silu(z)) + RMSNorm + norm_w, output bf16 (padded) ----
__global__ __launch_bounds__(256) void k_norm(const float* __restrict__ ybuf,
                                              const float* __restrict__ zx,
                                              const float* __restrict__ normw,
                                              unsigned short* __restrict__ ynb) {
    int row = blockIdx.x;
    int t = threadIdx.x;
    if (row >= TOKENS) {
        #pragma unroll
        for (int j = 0; j < 8; ++j) ynb[(size_t)row * DINNER + t + j * 256] = 0;
        return;
    }
    float v[8];
    float ss = 0.f;
    #pragma unroll
    for (int j = 0; j < 8; ++j) {
        int col = t + j * 256;
        float y = ybuf[(size_t)row * DINNER + col];
        float z = zx[(size_t)row * NPROJ + col];
        y *= z / (1.f + expf(-z));
        v[j] = y;
        ss += y * y;
    }
    #pragma unroll
    for (int off = 32; off > 0; off >>= 1) ss += __shfl_down(ss, off, 64);
    __shared__ float red[4];
    int lane = t & 63, wv = t >> 6;
    if (lane == 0) red[wv] = ss;
    __syncthreads();
    float tot = red[0] + red[1] + red[2] + red[3];
    float r = rsqrtf(tot * (1.f / DINNER) + 1e-5f);
    #pragma unroll
    for (int j = 0; j < 8; ++j) {
        int col = t + j * 256;
        ynb[(size_t)row * DINNER + col] = f2bf(v[j] * r * normw[col]);
    }
}

extern "C" void kernel_launch(void* const* d_in, const int* in_sizes, int n_in,
                              void* d_out, int out_size, void* d_ws, size_t ws_size,
                              hipStream_t stream) {
    const float* x       = (const float*)d_in[0];
    const float* W_in    = (const float*)d_in[1];
    const float* conv_w  = (const float*)d_in[2];
    const float* conv_b  = (const float*)d_in[3];
    const float* dt_bias = (const float*)d_in[4];
    const float* A_log   = (const float*)d_in[5];
    const float* Dp      = (const float*)d_in[6];
    const float* norm_w  = (const float*)d_in[7];
    const float* W_out   = (const float*)d_in[8];
    float* out = (float*)d_out;

    char* w = (char*)d_ws;
    auto alloc = [&](size_t bytes) {
        char* p = w;
        w += (bytes + 255) & ~(size_t)255;
        return p;
    };
    unsigned short* xb    = (unsigned short*)alloc((size_t)MPAD * DMODEL * 2);
    unsigned short* winb  = (unsigned short*)alloc((size_t)NPAD1 * DMODEL * 2);
    unsigned short* woutb = (unsigned short*)alloc((size_t)DMODEL * DINNER * 2);
    float* zx   = (float*)alloc((size_t)TOKENS * NPROJ * 4);   // also split-K partials for GEMM2
    float* xbc  = (float*)alloc((size_t)TOKENS * CONVDIM * 4);
    float* dtv  = (float*)alloc((size_t)TOKENS * NHEADS * 4);
    float* yb   = (float*)alloc((size_t)TOKENS * DINNER * 4);
    unsigned short* ynb = (unsigned short*)alloc((size_t)MPAD * DINNER * 2);
    float* Sg   = (float*)alloc((size_t)BATCHN * NHEADS * NCH * HEADDIM * DSTATE * 4);
    float* cumA = (float*)alloc((size_t)BATCHN * NHEADS * NCH * 64 * 4);

    int n4;
    n4 = MPAD * DMODEL / 4;
    k_f2bf_pad<<<(n4 + 255) / 256, 256, 0, stream>>>(x, xb, TOKENS * DMODEL / 4, n4);
    n4 = NPAD1 * DMODEL / 4;
    k_f2bf_pad<<<(n4 + 255) / 256, 256, 0, stream>>>(W_in, winb, NPROJ * DMODEL / 4, n4);
    n4 = DMODEL * DINNER / 4;
    k_f2bf_pad<<<(n4 + 255) / 256, 256, 0, stream>>>(W_out, woutb, n4, n4);
    k_dt<<<TOKENS / 8, 256, 0, stream>>>(x, W_in, dt_bias, dtv);
    // GEMM1: zx[2000][4384] = xb[2048][1024] * winb[4480][1024]^T
    dim3 g1(NPAD1 / 128, MPAD / 128, 1);
    k_gemmd<<<g1, 256, 0, stream>>>(xb, winb, zx, TOKENS, NPROJ, DMODEL, DMODEL, 0);
    k_conv4<<<(TOKENS / 4) * CONVDIM / 256, 256, 0, stream>>>(zx, conv_w, conv_b, xbc);
    k_tile<<<BATCHN * NHEADS * NCH, 256, 0, stream>>>(xbc, dtv, A_log, Dp, yb, Sg, cumA);
    k_scan2v<<<BATCHN * NHEADS * 32, 256, 0, stream>>>(Sg, cumA);
    k_yoff<<<BATCHN * NHEADS * NCH, 256, 0, stream>>>(xbc, Sg, cumA, yb);
    k_norm<<<MPAD, 256, 0, stream>>>(yb, zx, norm_w, ynb);
    // GEMM2 split-K=4: partials into zx (dead after k_norm), then reduce
    size_t pstride = (size_t)MPAD * DMODEL;
    dim3 g2(DMODEL / 128, MPAD / 128, 4);
    k_gemmd<<<g2, 256, 0, stream>>>(ynb, woutb, zx, MPAD, DMODEL, DINNER, DINNER / 4, pstride);
    n4 = TOKENS * DMODEL / 4;
    k_red<<<(n4 + 255) / 256, 256, 0, stream>>>(zx, out, n4, pstride / 4);
}

// Round 15
// 183.122 us; speedup vs baseline: 1.0460x; 1.0183x over previous
//
#include <hip/hip_runtime.h>
#include <hip/hip_bf16.h>

#define BATCHN 2
#define SEQL 1000
#define DMODEL 1024
#define DSTATE 128
#define HEADDIM 64
#define DINNER 2048
#define NHEADS 32
#define CONVDIM 2304   // DINNER + 2*DSTATE
#define NPROJ 4384     // 2*DINNER + 2*DSTATE + NHEADS
#define TOKENS 2000
#define MPAD 2048      // tokens padded to 128 multiple
#define NPAD1 4480     // NPROJ padded to 128 multiple
#define QC 64          // SSD chunk length
#define NCH 16         // chunks per sequence

typedef __bf16 bfx8 __attribute__((ext_vector_type(8)));
typedef float fx4 __attribute__((ext_vector_type(4)));
typedef unsigned short u16x8 __attribute__((ext_vector_type(8)));

__device__ __forceinline__ unsigned short f2bf(float f) {
    unsigned int u = __builtin_bit_cast(unsigned int, f);
    u += 0x7FFFu + ((u >> 16) & 1u);
    return (unsigned short)(u >> 16);
}
__device__ __forceinline__ float bf2f(unsigned short u) {
    return __builtin_bit_cast(float, ((unsigned int)u) << 16);
}

__device__ __forceinline__ void gload16(const void* g, void* l) {
    __builtin_amdgcn_global_load_lds(
        (const __attribute__((address_space(1))) void*)g,
        (__attribute__((address_space(3))) void*)l, 16, 0, 0);
}

// ---------------- fused fp32->bf16 for x, W_in, W_out (one launch) -----------
#define N4_X   (MPAD * DMODEL / 4)
#define N4_WIN (NPAD1 * DMODEL / 4)
#define N4_WO  (DMODEL * DINNER / 4)
__global__ __launch_bounds__(256) void k_f2bf3(const float* __restrict__ x,
                                               const float* __restrict__ win,
                                               const float* __restrict__ wout,
                                               unsigned short* __restrict__ xb,
                                               unsigned short* __restrict__ winb,
                                               unsigned short* __restrict__ woutb) {
    const int total = N4_X + N4_WIN + N4_WO;
    for (int i = blockIdx.x * 256 + threadIdx.x; i < total; i += gridDim.x * 256) {
        const float4* src;
        ushort4* dst;
        bool pad = false;
        if (i < N4_X) {
            pad = (i >= TOKENS * DMODEL / 4);
            src = ((const float4*)x) + i;
            dst = ((ushort4*)xb) + i;
        } else if (i < N4_X + N4_WIN) {
            int j = i - N4_X;
            pad = (j >= NPROJ * DMODEL / 4);
            src = ((const float4*)win) + j;
            dst = ((ushort4*)winb) + j;
        } else {
            int j = i - N4_X - N4_WIN;
            src = ((const float4*)wout) + j;
            dst = ((ushort4*)woutb) + j;
        }
        ushort4 o = {0, 0, 0, 0};
        if (!pad) {
            float4 v = *src;
            o.x = f2bf(v.x); o.y = f2bf(v.y); o.z = f2bf(v.z); o.w = f2bf(v.w);
        }
        *dst = o;
    }
}

// ---------------- dt head projection in fp32 (exp-sensitive path) ----------------
__global__ __launch_bounds__(256) void k_dt(const float* __restrict__ x,
                                            const float* __restrict__ win,
                                            const float* __restrict__ dt_bias,
                                            float* __restrict__ dtv) {
    __shared__ float sx[8][1024];
    int t = threadIdx.x;
    int tok0 = blockIdx.x * 8;
    for (int i = t; i < 8 * 256; i += 256) {
        int tok = i >> 8, k4 = i & 255;
        ((float4*)&sx[tok][0])[k4] = ((const float4*)(x + (size_t)(tok0 + tok) * DMODEL))[k4];
    }
    __syncthreads();
    int tl = t >> 5, h = t & 31;
    const float4* wr_ = (const float4*)(win + (size_t)(2 * DINNER + 2 * DSTATE + h) * DMODEL);
    const float4* xr = (const float4*)&sx[tl][0];
    float acc = 0.f;
    #pragma unroll 4
    for (int k = 0; k < 256; ++k) {
        float4 a = xr[k], b = wr_[k];
        acc += a.x * b.x + a.y * b.y + a.z * b.z + a.w * b.w;
    }
    float v = acc + dt_bias[h];
    dtv[(size_t)(tok0 + tl) * NHEADS + h] = fmaxf(v, 0.f) + log1pf(expf(-fabsf(v)));
}

// ---------------- bf16 NT GEMM: 128x128 tile, 256 thr, dbuf-2, swizzled -------
// (proven-best GEMM of 8 variants; used for GEMM1 only.)
__global__ __launch_bounds__(256) void k_gemmd(const unsigned short* __restrict__ A,
                                               const unsigned short* __restrict__ B,
                                               float* __restrict__ C,
                                               int Mstore, int N, int K) {
    __shared__ __attribute__((aligned(16))) unsigned short As[2][4096];  // 128x32
    __shared__ __attribute__((aligned(16))) unsigned short Bs[2][4096];
    int t = threadIdx.x;
    int lane = t & 63, wave = t >> 6;
    int wr = wave >> 1, wc = wave & 1;
    int m0 = blockIdx.y * 128, n0 = blockIdx.x * 128;
    int swcol = (((t & 3) ^ ((t >> 3) & 3)) * 8);
    const unsigned short* Ag = A + (size_t)(m0 + (t >> 2)) * K + swcol;
    const unsigned short* Bg = B + (size_t)(n0 + (t >> 2)) * K + swcol;
    int fr = lane & 15, ks = lane >> 4;
    int sl = (ks ^ ((fr >> 1) & 3)) << 3;
    fx4 acc[4][4] = {};
    gload16(Ag, &As[0][t * 8]);
    gload16(Ag + (size_t)64 * K, &As[0][2048 + t * 8]);
    gload16(Bg, &Bs[0][t * 8]);
    gload16(Bg + (size_t)64 * K, &Bs[0][2048 + t * 8]);
    __syncthreads();
    int cur = 0;
    for (int kk = 32; kk < K; kk += 32) {
        gload16(Ag + kk, &As[cur ^ 1][t * 8]);
        gload16(Ag + (size_t)64 * K + kk, &As[cur ^ 1][2048 + t * 8]);
        gload16(Bg + kk, &Bs[cur ^ 1][t * 8]);
        gload16(Bg + (size_t)64 * K + kk, &Bs[cur ^ 1][2048 + t * 8]);
        bfx8 a[4], b[4];
        #pragma unroll
        for (int m = 0; m < 4; ++m)
            a[m] = *(const bfx8*)&As[cur][(wr * 64 + m * 16 + fr) * 32 + sl];
        #pragma unroll
        for (int n = 0; n < 4; ++n)
            b[n] = *(const bfx8*)&Bs[cur][(wc * 64 + n * 16 + fr) * 32 + sl];
        #pragma unroll
        for (int m = 0; m < 4; ++m)
            #pragma unroll
            for (int n = 0; n < 4; ++n)
                acc[m][n] = __builtin_amdgcn_mfma_f32_16x16x32_bf16(a[m], b[n], acc[m][n], 0, 0, 0);
        __syncthreads();
        cur ^= 1;
    }
    {
        bfx8 a[4], b[4];
        #pragma unroll
        for (int m = 0; m < 4; ++m)
            a[m] = *(const bfx8*)&As[cur][(wr * 64 + m * 16 + fr) * 32 + sl];
        #pragma unroll
        for (int n = 0; n < 4; ++n)
            b[n] = *(const bfx8*)&Bs[cur][(wc * 64 + n * 16 + fr) * 32 + sl];
        #pragma unroll
        for (int m = 0; m < 4; ++m)
            #pragma unroll
            for (int n = 0; n < 4; ++n)
                acc[m][n] = __builtin_amdgcn_mfma_f32_16x16x32_bf16(a[m], b[n], acc[m][n], 0, 0, 0);
    }
    #pragma unroll
    for (int m = 0; m < 4; ++m) {
        int rbase = m0 + wr * 64 + m * 16 + (lane >> 4) * 4;
        #pragma unroll
        for (int i = 0; i < 4; ++i) {
            int r = rbase + i;
            if (r < Mstore) {
                #pragma unroll
                for (int n = 0; n < 4; ++n) {
                    int c = n0 + wc * 64 + n * 16 + fr;
                    if (c < N) C[(size_t)r * N + c] = acc[m][n][i];
                }
            }
        }
    }
}

// ---------------- GEMM2: 64x128 tile, 256 thr, dbuf-2, full-K, direct store ---
// (r8-proven; grid (N/128, M/64) = 256 blocks; no split-K, no reduce pass.)
__global__ __launch_bounds__(256) void k_gemmB(const unsigned short* __restrict__ A,
                                               const unsigned short* __restrict__ B,
                                               float* __restrict__ C,
                                               int Mstore, int N, int K) {
    __shared__ __attribute__((aligned(16))) unsigned short As[2][2048];  // 64x32
    __shared__ __attribute__((aligned(16))) unsigned short Bs[2][4096];  // 128x32
    int t = threadIdx.x;
    int lane = t & 63, wave = t >> 6;
    int wr = wave >> 1, wc = wave & 1;
    int m0 = blockIdx.y * 64, n0 = blockIdx.x * 128;
    int swcol = (((t & 3) ^ ((t >> 3) & 3)) * 8);
    const unsigned short* Ag = A + (size_t)(m0 + (t >> 2)) * K + swcol;
    const unsigned short* Bg = B + (size_t)(n0 + (t >> 2)) * K + swcol;
    int fr = lane & 15, ks = lane >> 4;
    int sl = (ks ^ ((fr >> 1) & 3)) << 3;
    fx4 acc[2][4] = {};
    gload16(Ag, &As[0][t * 8]);
    gload16(Bg, &Bs[0][t * 8]);
    gload16(Bg + (size_t)64 * K, &Bs[0][2048 + t * 8]);
    __syncthreads();
    int cur = 0;
    for (int kk = 32; kk < K; kk += 32) {
        gload16(Ag + kk, &As[cur ^ 1][t * 8]);
        gload16(Bg + kk, &Bs[cur ^ 1][t * 8]);
        gload16(Bg + (size_t)64 * K + kk, &Bs[cur ^ 1][2048 + t * 8]);
        bfx8 a[2], b[4];
        #pragma unroll
        for (int m = 0; m < 2; ++m)
            a[m] = *(const bfx8*)&As[cur][(wr * 32 + m * 16 + fr) * 32 + sl];
        #pragma unroll
        for (int n = 0; n < 4; ++n)
            b[n] = *(const bfx8*)&Bs[cur][(wc * 64 + n * 16 + fr) * 32 + sl];
        #pragma unroll
        for (int m = 0; m < 2; ++m)
            #pragma unroll
            for (int n = 0; n < 4; ++n)
                acc[m][n] = __builtin_amdgcn_mfma_f32_16x16x32_bf16(a[m], b[n], acc[m][n], 0, 0, 0);
        __syncthreads();
        cur ^= 1;
    }
    {
        bfx8 a[2], b[4];
        #pragma unroll
        for (int m = 0; m < 2; ++m)
            a[m] = *(const bfx8*)&As[cur][(wr * 32 + m * 16 + fr) * 32 + sl];
        #pragma unroll
        for (int n = 0; n < 4; ++n)
            b[n] = *(const bfx8*)&Bs[cur][(wc * 64 + n * 16 + fr) * 32 + sl];
        #pragma unroll
        for (int m = 0; m < 2; ++m)
            #pragma unroll
            for (int n = 0; n < 4; ++n)
                acc[m][n] = __builtin_amdgcn_mfma_f32_16x16x32_bf16(a[m], b[n], acc[m][n], 0, 0, 0);
    }
    #pragma unroll
    for (int m = 0; m < 2; ++m) {
        int rbase = m0 + wr * 32 + m * 16 + (lane >> 4) * 4;
        #pragma unroll
        for (int i = 0; i < 4; ++i) {
            int r = rbase + i;
            if (r < Mstore) {
                #pragma unroll
                for (int n = 0; n < 4; ++n) {
                    int c = n0 + wc * 64 + n * 16 + fr;
                    C[(size_t)r * N + c] = acc[m][n][i];
                }
            }
        }
    }
}

// ---------------- depthwise causal conv: 4 tokens/thread, register window -----
__global__ __launch_bounds__(256) void k_conv4(const float* __restrict__ zx,
                                               const float* __restrict__ cw,
                                               const float* __restrict__ cb,
                                               float* __restrict__ xbc) {
    int idx = blockIdx.x * 256 + threadIdx.x;
    if (idx >= (TOKENS / 4) * CONVDIM) return;
    int tg = idx / CONVDIM;
    int col = idx - tg * CONVDIM;
    int b = tg / 250;
    int l0 = (tg - b * 250) * 4;
    float in[7];
    #pragma unroll
    for (int j = 0; j < 7; ++j) {
        int lj = l0 - 3 + j;
        in[j] = (lj >= 0) ? zx[(size_t)(b * SEQL + lj) * NPROJ + DINNER + col] : 0.f;
    }
    float w0 = cw[col * 4], w1 = cw[col * 4 + 1], w2 = cw[col * 4 + 2], w3 = cw[col * 4 + 3];
    float bb = cb[col];
    #pragma unroll
    for (int i = 0; i < 4; ++i) {
        float a = bb + w0 * in[i] + w1 * in[i + 1] + w2 * in[i + 2] + w3 * in[i + 3];
        xbc[(size_t)(b * SEQL + l0 + i) * CONVDIM + col] = a / (1.f + expf(-a));
    }
}

// ================= SSD via MFMA, chunk = 64 =================
#define SCW 136
#define SWW 72
__global__ __launch_bounds__(256) void k_tile(const float* __restrict__ xbc,
                                              const float* __restrict__ dtv,
                                              const float* __restrict__ A_log,
                                              const float* __restrict__ Dp,
                                              float* __restrict__ ybuf,
                                              float* __restrict__ Sg,
                                              float* __restrict__ cumA) {
    __shared__ unsigned short sC[64 * SCW];
    __shared__ unsigned short sB[64 * SCW];   // reused as W [64*SWW] after G
    __shared__ unsigned short sBdT[128 * SWW];
    __shared__ unsigned short sXdT[64 * SWW];
    __shared__ unsigned short sXr[64 * SWW];
    __shared__ float sAcs[64];
    __shared__ float sdt[64];
    int bid = blockIdx.x;
    int h = bid & 31;
    int tmp = bid >> 5;
    int c = tmp & 15;
    int b = tmp >> 4;
    size_t lin = (size_t)((b * NHEADS + h) * NCH + c);   // logical Sg/cumA index
    int t = threadIdx.x;
    int lane = t & 63, wave = t >> 6;
    if (t < 64) {
        int tok = c * QC + t;
        float d = (tok < SEQL) ? dtv[(size_t)(b * SEQL + tok) * NHEADS + h] : 0.f;
        float A = -expf(A_log[h]);
        float v = A * d;
        #pragma unroll
        for (int off = 1; off < 64; off <<= 1) {
            float u = __shfl_up(v, off, 64);
            if (lane >= off) v += u;
        }
        sdt[t] = d;
        sAcs[t] = v;
        cumA[lin * 64 + t] = v;
    }
    __syncthreads();
    float Aend = sAcs[63];
    for (int i = t; i < 64 * 32; i += 256) {
        int l = i >> 5, n4 = (i & 31) * 4;
        int tok = c * QC + l;
        float4 cv = {0, 0, 0, 0}, bv = {0, 0, 0, 0};
        if (tok < SEQL) {
            const float* base = xbc + (size_t)(b * SEQL + tok) * CONVDIM;
            bv = *(const float4*)(base + DINNER + n4);
            cv = *(const float4*)(base + DINNER + DSTATE + n4);
        }
        float dec = expf(Aend - sAcs[l]);
        sC[l * SCW + n4 + 0] = f2bf(cv.x); sC[l * SCW + n4 + 1] = f2bf(cv.y);
        sC[l * SCW + n4 + 2] = f2bf(cv.z); sC[l * SCW + n4 + 3] = f2bf(cv.w);
        sB[l * SCW + n4 + 0] = f2bf(bv.x); sB[l * SCW + n4 + 1] = f2bf(bv.y);
        sB[l * SCW + n4 + 2] = f2bf(bv.z); sB[l * SCW + n4 + 3] = f2bf(bv.w);
        sBdT[(n4 + 0) * SWW + l] = f2bf(bv.x * dec);
        sBdT[(n4 + 1) * SWW + l] = f2bf(bv.y * dec);
        sBdT[(n4 + 2) * SWW + l] = f2bf(bv.z * dec);
        sBdT[(n4 + 3) * SWW + l] = f2bf(bv.w * dec);
    }
    for (int i = t; i < 64 * 16; i += 256) {
        int l = i >> 4, p4 = (i & 15) * 4;
        int tok = c * QC + l;
        float4 xv = {0, 0, 0, 0};
        if (tok < SEQL) xv = *(const float4*)(xbc + (size_t)(b * SEQL + tok) * CONVDIM + h * 64 + p4);
        float d = sdt[l];
        sXr[l * SWW + p4 + 0] = f2bf(xv.x); sXr[l * SWW + p4 + 1] = f2bf(xv.y);
        sXr[l * SWW + p4 + 2] = f2bf(xv.z); sXr[l * SWW + p4 + 3] = f2bf(xv.w);
        sXdT[(p4 + 0) * SWW + l] = f2bf(xv.x * d);
        sXdT[(p4 + 1) * SWW + l] = f2bf(xv.y * d);
        sXdT[(p4 + 2) * SWW + l] = f2bf(xv.z * d);
        sXdT[(p4 + 3) * SWW + l] = f2bf(xv.w * d);
    }
    __syncthreads();
    int fr = lane & 15, fk8 = (lane >> 4) * 8;
    int wr = wave >> 1, wc = wave & 1;
    fx4 g[2][2] = {};
    #pragma unroll
    for (int k = 0; k < 4; ++k) {
        bfx8 a0 = *(const bfx8*)&sC[(wr * 32 + fr) * SCW + k * 32 + fk8];
        bfx8 a1 = *(const bfx8*)&sC[(wr * 32 + 16 + fr) * SCW + k * 32 + fk8];
        bfx8 b0 = *(const bfx8*)&sB[(wc * 32 + fr) * SCW + k * 32 + fk8];
        bfx8 b1 = *(const bfx8*)&sB[(wc * 32 + 16 + fr) * SCW + k * 32 + fk8];
        g[0][0] = __builtin_amdgcn_mfma_f32_16x16x32_bf16(a0, b0, g[0][0], 0, 0, 0);
        g[0][1] = __builtin_amdgcn_mfma_f32_16x16x32_bf16(a0, b1, g[0][1], 0, 0, 0);
        g[1][0] = __builtin_amdgcn_mfma_f32_16x16x32_bf16(a1, b0, g[1][0], 0, 0, 0);
        g[1][1] = __builtin_amdgcn_mfma_f32_16x16x32_bf16(a1, b1, g[1][1], 0, 0, 0);
    }
    __syncthreads();
    int rb = wr * 32 + (lane >> 4) * 4;
    int cb = wc * 32 + fr;
    #pragma unroll
    for (int m = 0; m < 2; ++m)
        #pragma unroll
        for (int n = 0; n < 2; ++n)
            #pragma unroll
            for (int i = 0; i < 4; ++i) {
                int row = rb + m * 16 + i, col = cb + n * 16;
                float wv = (col <= row) ? g[m][n][i] * expf(sAcs[row] - sAcs[col]) : 0.f;
                sB[row * SWW + col] = f2bf(wv);
            }
    __syncthreads();
    fx4 yd[2][2] = {};
    fx4 sc[2][4] = {};
    #pragma unroll
    for (int k = 0; k < 2; ++k) {
        bfx8 aW0 = *(const bfx8*)&sB[(wr * 32 + fr) * SWW + k * 32 + fk8];
        bfx8 aW1 = *(const bfx8*)&sB[(wr * 32 + 16 + fr) * SWW + k * 32 + fk8];
        bfx8 bX0 = *(const bfx8*)&sXdT[(wc * 32 + fr) * SWW + k * 32 + fk8];
        bfx8 bX1 = *(const bfx8*)&sXdT[(wc * 32 + 16 + fr) * SWW + k * 32 + fk8];
        yd[0][0] = __builtin_amdgcn_mfma_f32_16x16x32_bf16(aW0, bX0, yd[0][0], 0, 0, 0);
        yd[0][1] = __builtin_amdgcn_mfma_f32_16x16x32_bf16(aW0, bX1, yd[0][1], 0, 0, 0);
        yd[1][0] = __builtin_amdgcn_mfma_f32_16x16x32_bf16(aW1, bX0, yd[1][0], 0, 0, 0);
        yd[1][1] = __builtin_amdgcn_mfma_f32_16x16x32_bf16(aW1, bX1, yd[1][1], 0, 0, 0);
        bfx8 aX0 = *(const bfx8*)&sXdT[(wr * 32 + fr) * SWW + k * 32 + fk8];
        bfx8 aX1 = *(const bfx8*)&sXdT[(wr * 32 + 16 + fr) * SWW + k * 32 + fk8];
        #pragma unroll
        for (int j = 0; j < 4; ++j) {
            bfx8 bB = *(const bfx8*)&sBdT[(wc * 64 + j * 16 + fr) * SWW + k * 32 + fk8];
            sc[0][j] = __builtin_amdgcn_mfma_f32_16x16x32_bf16(aX0, bB, sc[0][j], 0, 0, 0);
            sc[1][j] = __builtin_amdgcn_mfma_f32_16x16x32_bf16(aX1, bB, sc[1][j], 0, 0, 0);
        }
    }
    float Dh = Dp[h];
    #pragma unroll
    for (int m = 0; m < 2; ++m)
        #pragma unroll
        for (int i = 0; i < 4; ++i) {
            int row = rb + m * 16 + i;
            int tok = c * QC + row;
            if (tok < SEQL) {
                #pragma unroll
                for (int n = 0; n < 2; ++n) {
                    int col = cb + n * 16;
                    float xr = bf2f(sXr[row * SWW + col]);
                    ybuf[(size_t)(b * SEQL + tok) * DINNER + h * 64 + col] = yd[m][n][i] + Dh * xr;
                }
            }
        }
    #pragma unroll
    for (int m = 0; m < 2; ++m)
        #pragma unroll
        for (int i = 0; i < 4; ++i) {
            int p = rb + m * 16 + i;
            #pragma unroll
            for (int j = 0; j < 4; ++j) {
                int n = wc * 64 + j * 16 + fr;
                Sg[lin * 8192 + p * 128 + n] = sc[m][j][i];
            }
        }
}

__global__ __launch_bounds__(256) void k_scan2v(float* __restrict__ Sg,
                                                const float* __restrict__ cumA) {
    int bid = blockIdx.x;
    int bh = bid >> 5, sub = bid & 31;
    int e = sub * 256 + threadIdx.x;
    __shared__ float sT[NCH];
    if (threadIdx.x < NCH)
        sT[threadIdx.x] = cumA[((size_t)(bh * NCH) + threadIdx.x) * 64 + 63];
    __syncthreads();
    float S = 0.f;
    size_t base = (size_t)bh * NCH * 8192 + e;
    for (int g = 0; g < NCH; ++g) {
        size_t off = base + (size_t)g * 8192;
        float sg = Sg[off];
        Sg[off] = S;
        S = expf(sT[g]) * S + sg;
    }
}

__global__ __launch_bounds__(256) void k_yoff(const float* __restrict__ xbc,
                                              const float* __restrict__ Sg,
                                              const float* __restrict__ cumA,
                                              float* __restrict__ ybuf) {
    int bid = blockIdx.x;
    int h = bid & 31;
    int tmp = bid >> 5;
    int c = tmp & 15;
    int b = tmp >> 4;
    if (c == 0) return;
    size_t lin = (size_t)((b * NHEADS + h) * NCH + c);
    __shared__ unsigned short sC[64 * SCW];
    __shared__ unsigned short sS[64 * SCW];
    __shared__ float sE[64];
    int t = threadIdx.x;
    int lane = t & 63, wave = t >> 6;
    if (t < 64) sE[t] = expf(cumA[lin * 64 + t]);
    for (int i = t; i < 64 * 32; i += 256) {
        int l = i >> 5, n4 = (i & 31) * 4;
        int tok = c * QC + l;
        float4 cv = {0, 0, 0, 0};
        if (tok < SEQL)
            cv = *(const float4*)(xbc + (size_t)(b * SEQL + tok) * CONVDIM + DINNER + DSTATE + n4);
        sC[l * SCW + n4 + 0] = f2bf(cv.x); sC[l * SCW + n4 + 1] = f2bf(cv.y);
        sC[l * SCW + n4 + 2] = f2bf(cv.z); sC[l * SCW + n4 + 3] = f2bf(cv.w);
        float4 sv = *(const float4*)(Sg + lin * 8192 + l * 128 + n4);
        sS[l * SCW + n4 + 0] = f2bf(sv.x); sS[l * SCW + n4 + 1] = f2bf(sv.y);
        sS[l * SCW + n4 + 2] = f2bf(sv.z); sS[l * SCW + n4 + 3] = f2bf(sv.w);
    }
    __syncthreads();
    int fr = lane & 15, fk8 = (lane >> 4) * 8;
    int wr = wave >> 1, wc = wave & 1;
    fx4 yo[2][2] = {};
    #pragma unroll
    for (int k = 0; k < 4; ++k) {
        bfx8 a0 = *(const bfx8*)&sC[(wr * 32 + fr) * SCW + k * 32 + fk8];
        bfx8 a1 = *(const bfx8*)&sC[(wr * 32 + 16 + fr) * SCW + k * 32 + fk8];
        bfx8 b0 = *(const bfx8*)&sS[(wc * 32 + fr) * SCW + k * 32 + fk8];
        bfx8 b1 = *(const bfx8*)&sS[(wc * 32 + 16 + fr) * SCW + k * 32 + fk8];
        yo[0][0] = __builtin_amdgcn_mfma_f32_16x16x32_bf16(a0, b0, yo[0][0], 0, 0, 0);
        yo[0][1] = __builtin_amdgcn_mfma_f32_16x16x32_bf16(a0, b1, yo[0][1], 0, 0, 0);
        yo[1][0] = __builtin_amdgcn_mfma_f32_16x16x32_bf16(a1, b0, yo[1][0], 0, 0, 0);
        yo[1][1] = __builtin_amdgcn_mfma_f32_16x16x32_bf16(a1, b1, yo[1][1], 0, 0, 0);
    }
    int rb = wr * 32 + (lane >> 4) * 4;
    int cb = wc * 32 + fr;
    #pragma unroll
    for (int m = 0; m < 2; ++m)
        #pragma unroll
        for (int i = 0; i < 4; ++i) {
            int row = rb + m * 16 + i;
            int tok = c * QC + row;
            if (tok < SEQL) {
                float e = sE[row];
                #pragma unroll
                for (int n = 0; n < 2; ++n) {
                    int col = cb + n * 16;
                    size_t off = (size_t)(b * SEQL + tok) * DINNER + h * 64 + col;
                    ybuf[off] += yo[m][n][i] * e;
                }
            }
        }
}

// ---------------- gate (y * silu(z)) + RMSNorm + norm_w, output bf16 (padded) ----
__global__ __launch_bounds__(256) void k_norm(const float* __restrict__ ybuf,
                                              const float* __restrict__ zx,
                                              const float* __restrict__ normw,
                                              unsigned short* __restrict__ ynb) {
    int row = blockIdx.x;
    int t = threadIdx.x;
    if (row >= TOKENS) {
        #pragma unroll
        for (int j = 0; j < 8; ++j) ynb[(size_t)row * DINNER + t + j * 256] = 0;
        return;
    }
    float v[8];
    float ss = 0.f;
    #pragma unroll
    for (int j = 0; j < 8; ++j) {
        int col = t + j * 256;
        float y = ybuf[(size_t)row * DINNER + col];
        float z = zx[(size_t)row * NPROJ + col];
        y *= z / (1.f + expf(-z));
        v[j] = y;
        ss += y * y;
    }
    #pragma unroll
    for (int off = 32; off > 0; off >>= 1) ss += __shfl_down(ss, off, 64);
    __shared__ float red[4];
    int lane = t & 63, wv = t >> 6;
    if (lane == 0) red[wv] = ss;
    __syncthreads();
    float tot = red[0] + red[1] + red[2] + red[3];
    float r = rsqrtf(tot * (1.f / DINNER) + 1e-5f);
    #pragma unroll
    for (int j = 0; j < 8; ++j) {
        int col = t + j * 256;
        ynb[(size_t)row * DINNER + col] = f2bf(v[j] * r * normw[col]);
    }
}

extern "C" void kernel_launch(void* const* d_in, const int* in_sizes, int n_in,
                              void* d_out, int out_size, void* d_ws, size_t ws_size,
                              hipStream_t stream) {
    const float* x       = (const float*)d_in[0];
    const float* W_in    = (const float*)d_in[1];
    const float* conv_w  = (const float*)d_in[2];
    const float* conv_b  = (const float*)d_in[3];
    const float* dt_bias = (const float*)d_in[4];
    const float* A_log   = (const float*)d_in[5];
    const float* Dp      = (const float*)d_in[6];
    const float* norm_w  = (const float*)d_in[7];
    const float* W_out   = (const float*)d_in[8];
    float* out = (float*)d_out;

    char* w = (char*)d_ws;
    auto alloc = [&](size_t bytes) {
        char* p = w;
        w += (bytes + 255) & ~(size_t)255;
        return p;
    };
    unsigned short* xb    = (unsigned short*)alloc((size_t)MPAD * DMODEL * 2);
    unsigned short* winb  = (unsigned short*)alloc((size_t)NPAD1 * DMODEL * 2);
    unsigned short* woutb = (unsigned short*)alloc((size_t)DMODEL * DINNER * 2);
    float* zx   = (float*)alloc((size_t)TOKENS * NPROJ * 4);
    float* xbc  = (float*)alloc((size_t)TOKENS * CONVDIM * 4);
    float* dtv  = (float*)alloc((size_t)TOKENS * NHEADS * 4);
    float* yb   = (float*)alloc((size_t)TOKENS * DINNER * 4);
    unsigned short* ynb = (unsigned short*)alloc((size_t)MPAD * DINNER * 2);
    float* Sg   = (float*)alloc((size_t)BATCHN * NHEADS * NCH * HEADDIM * DSTATE * 4);
    float* cumA = (float*)alloc((size_t)BATCHN * NHEADS * NCH * 64 * 4);

    k_f2bf3<<<2048, 256, 0, stream>>>(x, W_in, W_out, xb, winb, woutb);
    k_dt<<<TOKENS / 8, 256, 0, stream>>>(x, W_in, dt_bias, dtv);
    // GEMM1: zx[2000][4384] = xb[2048][1024] * winb[4480][1024]^T
    dim3 g1(NPAD1 / 128, MPAD / 128);
    k_gemmd<<<g1, 256, 0, stream>>>(xb, winb, zx, TOKENS, NPROJ, DMODEL);
    k_conv4<<<(TOKENS / 4) * CONVDIM / 256, 256, 0, stream>>>(zx, conv_w, conv_b, xbc);
    k_tile<<<BATCHN * NHEADS * NCH, 256, 0, stream>>>(xbc, dtv, A_log, Dp, yb, Sg, cumA);
    k_scan2v<<<BATCHN * NHEADS * 32, 256, 0, stream>>>(Sg, cumA);
    k_yoff<<<BATCHN * NHEADS * NCH, 256, 0, stream>>>(xbc, Sg, cumA, yb);
    k_norm<<<MPAD, 256, 0, stream>>>(yb, zx, norm_w, ynb);
    // GEMM2: out[2000][1024] = ynb[2048][2048] * woutb[1024][2048]^T, full-K, no reduce
    dim3 g2(DMODEL / 128, MPAD / 64);
    k_gemmB<<<g2, 256, 0, stream>>>(ynb, woutb, out, TOKENS, DMODEL, DINNER);
}

// Round 16
// 182.203 us; speedup vs baseline: 1.0512x; 1.0050x over previous
//
#include <hip/hip_runtime.h>
#include <hip/hip_bf16.h>

#define BATCHN 2
#define SEQL 1000
#define DMODEL 1024
#define DSTATE 128
#define HEADDIM 64
#define DINNER 2048
#define NHEADS 32
#define CONVDIM 2304   // DINNER + 2*DSTATE
#define NPROJ 4384     // 2*DINNER + 2*DSTATE + NHEADS
#define TOKENS 2000
#define MPAD 2048      // tokens padded to 128 multiple
#define NPAD1 4480     // NPROJ padded to 128 multiple
#define QC 64          // SSD chunk length
#define NCH 16         // chunks per sequence

typedef __bf16 bfx8 __attribute__((ext_vector_type(8)));
typedef float fx4 __attribute__((ext_vector_type(4)));
typedef unsigned short u16x8 __attribute__((ext_vector_type(8)));

__device__ __forceinline__ unsigned short f2bf(float f) {
    unsigned int u = __builtin_bit_cast(unsigned int, f);
    u += 0x7FFFu + ((u >> 16) & 1u);
    return (unsigned short)(u >> 16);
}
__device__ __forceinline__ float bf2f(unsigned short u) {
    return __builtin_bit_cast(float, ((unsigned int)u) << 16);
}

__device__ __forceinline__ void gload16(const void* g, void* l) {
    __builtin_amdgcn_global_load_lds(
        (const __attribute__((address_space(1))) void*)g,
        (__attribute__((address_space(3))) void*)l, 16, 0, 0);
}

// ---------------- fused fp32->bf16 for x, W_in, W_out (one launch) -----------
#define N4_X   (MPAD * DMODEL / 4)
#define N4_WIN (NPAD1 * DMODEL / 4)
#define N4_WO  (DMODEL * DINNER / 4)
__global__ __launch_bounds__(256) void k_f2bf3(const float* __restrict__ x,
                                               const float* __restrict__ win,
                                               const float* __restrict__ wout,
                                               unsigned short* __restrict__ xb,
                                               unsigned short* __restrict__ winb,
                                               unsigned short* __restrict__ woutb) {
    const int total = N4_X + N4_WIN + N4_WO;
    for (int i = blockIdx.x * 256 + threadIdx.x; i < total; i += gridDim.x * 256) {
        const float4* src;
        ushort4* dst;
        bool pad = false;
        if (i < N4_X) {
            pad = (i >= TOKENS * DMODEL / 4);
            src = ((const float4*)x) + i;
            dst = ((ushort4*)xb) + i;
        } else if (i < N4_X + N4_WIN) {
            int j = i - N4_X;
            pad = (j >= NPROJ * DMODEL / 4);
            src = ((const float4*)win) + j;
            dst = ((ushort4*)winb) + j;
        } else {
            int j = i - N4_X - N4_WIN;
            src = ((const float4*)wout) + j;
            dst = ((ushort4*)woutb) + j;
        }
        ushort4 o = {0, 0, 0, 0};
        if (!pad) {
            float4 v = *src;
            o.x = f2bf(v.x); o.y = f2bf(v.y); o.z = f2bf(v.z); o.w = f2bf(v.w);
        }
        *dst = o;
    }
}

// ---------------- dt head projection in fp32 (exp-sensitive path) ----------------
__global__ __launch_bounds__(256) void k_dt(const float* __restrict__ x,
                                            const float* __restrict__ win,
                                            const float* __restrict__ dt_bias,
                                            float* __restrict__ dtv) {
    __shared__ float sx[8][1024];
    int t = threadIdx.x;
    int tok0 = blockIdx.x * 8;
    for (int i = t; i < 8 * 256; i += 256) {
        int tok = i >> 8, k4 = i & 255;
        ((float4*)&sx[tok][0])[k4] = ((const float4*)(x + (size_t)(tok0 + tok) * DMODEL))[k4];
    }
    __syncthreads();
    int tl = t >> 5, h = t & 31;
    const float4* wr_ = (const float4*)(win + (size_t)(2 * DINNER + 2 * DSTATE + h) * DMODEL);
    const float4* xr = (const float4*)&sx[tl][0];
    float acc = 0.f;
    #pragma unroll 4
    for (int k = 0; k < 256; ++k) {
        float4 a = xr[k], b = wr_[k];
        acc += a.x * b.x + a.y * b.y + a.z * b.z + a.w * b.w;
    }
    float v = acc + dt_bias[h];
    dtv[(size_t)(tok0 + tl) * NHEADS + h] = fmaxf(v, 0.f) + log1pf(expf(-fabsf(v)));
}

// ---------------- bf16 NT GEMM: 128x128 tile, dbuf-2, swizzled, XCD-aware -----
// 1D grid (nbx*nby blocks, nbx*nby % 8 == 0); bijective XCD swizzle groups
// contiguous block runs per XCD so shared A-panels hit that XCD's L2.
__global__ __launch_bounds__(256) void k_gemmd(const unsigned short* __restrict__ A,
                                               const unsigned short* __restrict__ B,
                                               float* __restrict__ C,
                                               int Mstore, int N, int K, int nbx) {
    int nwg = gridDim.x;
    int cpx = nwg >> 3;                       // blocks per XCD (nwg % 8 == 0)
    int bid = blockIdx.x;
    int swz = (bid & 7) * cpx + (bid >> 3);   // contiguous run per XCD
    int bx = swz % nbx, by = swz / nbx;
    __shared__ __attribute__((aligned(16))) unsigned short As[2][4096];  // 128x32
    __shared__ __attribute__((aligned(16))) unsigned short Bs[2][4096];
    int t = threadIdx.x;
    int lane = t & 63, wave = t >> 6;
    int wr = wave >> 1, wc = wave & 1;
    int m0 = by * 128, n0 = bx * 128;
    int swcol = (((t & 3) ^ ((t >> 3) & 3)) * 8);
    const unsigned short* Ag = A + (size_t)(m0 + (t >> 2)) * K + swcol;
    const unsigned short* Bg = B + (size_t)(n0 + (t >> 2)) * K + swcol;
    int fr = lane & 15, ks = lane >> 4;
    int sl = (ks ^ ((fr >> 1) & 3)) << 3;
    fx4 acc[4][4] = {};
    gload16(Ag, &As[0][t * 8]);
    gload16(Ag + (size_t)64 * K, &As[0][2048 + t * 8]);
    gload16(Bg, &Bs[0][t * 8]);
    gload16(Bg + (size_t)64 * K, &Bs[0][2048 + t * 8]);
    __syncthreads();
    int cur = 0;
    for (int kk = 32; kk < K; kk += 32) {
        gload16(Ag + kk, &As[cur ^ 1][t * 8]);
        gload16(Ag + (size_t)64 * K + kk, &As[cur ^ 1][2048 + t * 8]);
        gload16(Bg + kk, &Bs[cur ^ 1][t * 8]);
        gload16(Bg + (size_t)64 * K + kk, &Bs[cur ^ 1][2048 + t * 8]);
        bfx8 a[4], b[4];
        #pragma unroll
        for (int m = 0; m < 4; ++m)
            a[m] = *(const bfx8*)&As[cur][(wr * 64 + m * 16 + fr) * 32 + sl];
        #pragma unroll
        for (int n = 0; n < 4; ++n)
            b[n] = *(const bfx8*)&Bs[cur][(wc * 64 + n * 16 + fr) * 32 + sl];
        #pragma unroll
        for (int m = 0; m < 4; ++m)
            #pragma unroll
            for (int n = 0; n < 4; ++n)
                acc[m][n] = __builtin_amdgcn_mfma_f32_16x16x32_bf16(a[m], b[n], acc[m][n], 0, 0, 0);
        __syncthreads();
        cur ^= 1;
    }
    {
        bfx8 a[4], b[4];
        #pragma unroll
        for (int m = 0; m < 4; ++m)
            a[m] = *(const bfx8*)&As[cur][(wr * 64 + m * 16 + fr) * 32 + sl];
        #pragma unroll
        for (int n = 0; n < 4; ++n)
            b[n] = *(const bfx8*)&Bs[cur][(wc * 64 + n * 16 + fr) * 32 + sl];
        #pragma unroll
        for (int m = 0; m < 4; ++m)
            #pragma unroll
            for (int n = 0; n < 4; ++n)
                acc[m][n] = __builtin_amdgcn_mfma_f32_16x16x32_bf16(a[m], b[n], acc[m][n], 0, 0, 0);
    }
    #pragma unroll
    for (int m = 0; m < 4; ++m) {
        int rbase = m0 + wr * 64 + m * 16 + (lane >> 4) * 4;
        #pragma unroll
        for (int i = 0; i < 4; ++i) {
            int r = rbase + i;
            if (r < Mstore) {
                #pragma unroll
                for (int n = 0; n < 4; ++n) {
                    int c = n0 + wc * 64 + n * 16 + fr;
                    if (c < N) C[(size_t)r * N + c] = acc[m][n][i];
                }
            }
        }
    }
}

// ---------------- GEMM2: 64x128 tile, dbuf-2, full-K, direct store, XCD-aware -
__global__ __launch_bounds__(256) void k_gemmB(const unsigned short* __restrict__ A,
                                               const unsigned short* __restrict__ B,
                                               float* __restrict__ C,
                                               int Mstore, int N, int K, int nbx) {
    int nwg = gridDim.x;
    int cpx = nwg >> 3;
    int bid = blockIdx.x;
    int swz = (bid & 7) * cpx + (bid >> 3);
    int bx = swz % nbx, by = swz / nbx;
    __shared__ __attribute__((aligned(16))) unsigned short As[2][2048];  // 64x32
    __shared__ __attribute__((aligned(16))) unsigned short Bs[2][4096];  // 128x32
    int t = threadIdx.x;
    int lane = t & 63, wave = t >> 6;
    int wr = wave >> 1, wc = wave & 1;
    int m0 = by * 64, n0 = bx * 128;
    int swcol = (((t & 3) ^ ((t >> 3) & 3)) * 8);
    const unsigned short* Ag = A + (size_t)(m0 + (t >> 2)) * K + swcol;
    const unsigned short* Bg = B + (size_t)(n0 + (t >> 2)) * K + swcol;
    int fr = lane & 15, ks = lane >> 4;
    int sl = (ks ^ ((fr >> 1) & 3)) << 3;
    fx4 acc[2][4] = {};
    gload16(Ag, &As[0][t * 8]);
    gload16(Bg, &Bs[0][t * 8]);
    gload16(Bg + (size_t)64 * K, &Bs[0][2048 + t * 8]);
    __syncthreads();
    int cur = 0;
    for (int kk = 32; kk < K; kk += 32) {
        gload16(Ag + kk, &As[cur ^ 1][t * 8]);
        gload16(Bg + kk, &Bs[cur ^ 1][t * 8]);
        gload16(Bg + (size_t)64 * K + kk, &Bs[cur ^ 1][2048 + t * 8]);
        bfx8 a[2], b[4];
        #pragma unroll
        for (int m = 0; m < 2; ++m)
            a[m] = *(const bfx8*)&As[cur][(wr * 32 + m * 16 + fr) * 32 + sl];
        #pragma unroll
        for (int n = 0; n < 4; ++n)
            b[n] = *(const bfx8*)&Bs[cur][(wc * 64 + n * 16 + fr) * 32 + sl];
        #pragma unroll
        for (int m = 0; m < 2; ++m)
            #pragma unroll
            for (int n = 0; n < 4; ++n)
                acc[m][n] = __builtin_amdgcn_mfma_f32_16x16x32_bf16(a[m], b[n], acc[m][n], 0, 0, 0);
        __syncthreads();
        cur ^= 1;
    }
    {
        bfx8 a[2], b[4];
        #pragma unroll
        for (int m = 0; m < 2; ++m)
            a[m] = *(const bfx8*)&As[cur][(wr * 32 + m * 16 + fr) * 32 + sl];
        #pragma unroll
        for (int n = 0; n < 4; ++n)
            b[n] = *(const bfx8*)&Bs[cur][(wc * 64 + n * 16 + fr) * 32 + sl];
        #pragma unroll
        for (int m = 0; m < 2; ++m)
            #pragma unroll
            for (int n = 0; n < 4; ++n)
                acc[m][n] = __builtin_amdgcn_mfma_f32_16x16x32_bf16(a[m], b[n], acc[m][n], 0, 0, 0);
    }
    #pragma unroll
    for (int m = 0; m < 2; ++m) {
        int rbase = m0 + wr * 32 + m * 16 + (lane >> 4) * 4;
        #pragma unroll
        for (int i = 0; i < 4; ++i) {
            int r = rbase + i;
            if (r < Mstore) {
                #pragma unroll
                for (int n = 0; n < 4; ++n) {
                    int c = n0 + wc * 64 + n * 16 + fr;
                    C[(size_t)r * N + c] = acc[m][n][i];
                }
            }
        }
    }
}

// ---------------- depthwise causal conv: 4 tokens/thread, register window -----
__global__ __launch_bounds__(256) void k_conv4(const float* __restrict__ zx,
                                               const float* __restrict__ cw,
                                               const float* __restrict__ cb,
                                               float* __restrict__ xbc) {
    int idx = blockIdx.x * 256 + threadIdx.x;
    if (idx >= (TOKENS / 4) * CONVDIM) return;
    int tg = idx / CONVDIM;
    int col = idx - tg * CONVDIM;
    int b = tg / 250;
    int l0 = (tg - b * 250) * 4;
    float in[7];
    #pragma unroll
    for (int j = 0; j < 7; ++j) {
        int lj = l0 - 3 + j;
        in[j] = (lj >= 0) ? zx[(size_t)(b * SEQL + lj) * NPROJ + DINNER + col] : 0.f;
    }
    float w0 = cw[col * 4], w1 = cw[col * 4 + 1], w2 = cw[col * 4 + 2], w3 = cw[col * 4 + 3];
    float bb = cb[col];
    #pragma unroll
    for (int i = 0; i < 4; ++i) {
        float a = bb + w0 * in[i] + w1 * in[i + 1] + w2 * in[i + 2] + w3 * in[i + 3];
        xbc[(size_t)(b * SEQL + l0 + i) * CONVDIM + col] = a / (1.f + expf(-a));
    }
}

// ================= SSD via MFMA, chunk = 64 =================
#define SCW 136
#define SWW 72
__global__ __launch_bounds__(256) void k_tile(const float* __restrict__ xbc,
                                              const float* __restrict__ dtv,
                                              const float* __restrict__ A_log,
                                              const float* __restrict__ Dp,
                                              float* __restrict__ ybuf,
                                              float* __restrict__ Sg,
                                              float* __restrict__ cumA) {
    __shared__ unsigned short sC[64 * SCW];
    __shared__ unsigned short sB[64 * SCW];   // reused as W [64*SWW] after G
    __shared__ unsigned short sBdT[128 * SWW];
    __shared__ unsigned short sXdT[64 * SWW];
    __shared__ unsigned short sXr[64 * SWW];
    __shared__ float sAcs[64];
    __shared__ float sdt[64];
    int bid = blockIdx.x;
    int h = bid & 31;
    int tmp = bid >> 5;
    int c = tmp & 15;
    int b = tmp >> 4;
    size_t lin = (size_t)((b * NHEADS + h) * NCH + c);   // logical Sg/cumA index
    int t = threadIdx.x;
    int lane = t & 63, wave = t >> 6;
    if (t < 64) {
        int tok = c * QC + t;
        float d = (tok < SEQL) ? dtv[(size_t)(b * SEQL + tok) * NHEADS + h] : 0.f;
        float A = -expf(A_log[h]);
        float v = A * d;
        #pragma unroll
        for (int off = 1; off < 64; off <<= 1) {
            float u = __shfl_up(v, off, 64);
            if (lane >= off) v += u;
        }
        sdt[t] = d;
        sAcs[t] = v;
        cumA[lin * 64 + t] = v;
    }
    __syncthreads();
    float Aend = sAcs[63];
    for (int i = t; i < 64 * 32; i += 256) {
        int l = i >> 5, n4 = (i & 31) * 4;
        int tok = c * QC + l;
        float4 cv = {0, 0, 0, 0}, bv = {0, 0, 0, 0};
        if (tok < SEQL) {
            const float* base = xbc + (size_t)(b * SEQL + tok) * CONVDIM;
            bv = *(const float4*)(base + DINNER + n4);
            cv = *(const float4*)(base + DINNER + DSTATE + n4);
        }
        float dec = expf(Aend - sAcs[l]);
        sC[l * SCW + n4 + 0] = f2bf(cv.x); sC[l * SCW + n4 + 1] = f2bf(cv.y);
        sC[l * SCW + n4 + 2] = f2bf(cv.z); sC[l * SCW + n4 + 3] = f2bf(cv.w);
        sB[l * SCW + n4 + 0] = f2bf(bv.x); sB[l * SCW + n4 + 1] = f2bf(bv.y);
        sB[l * SCW + n4 + 2] = f2bf(bv.z); sB[l * SCW + n4 + 3] = f2bf(bv.w);
        sBdT[(n4 + 0) * SWW + l] = f2bf(bv.x * dec);
        sBdT[(n4 + 1) * SWW + l] = f2bf(bv.y * dec);
        sBdT[(n4 + 2) * SWW + l] = f2bf(bv.z * dec);
        sBdT[(n4 + 3) * SWW + l] = f2bf(bv.w * dec);
    }
    for (int i = t; i < 64 * 16; i += 256) {
        int l = i >> 4, p4 = (i & 15) * 4;
        int tok = c * QC + l;
        float4 xv = {0, 0, 0, 0};
        if (tok < SEQL) xv = *(const float4*)(xbc + (size_t)(b * SEQL + tok) * CONVDIM + h * 64 + p4);
        float d = sdt[l];
        sXr[l * SWW + p4 + 0] = f2bf(xv.x); sXr[l * SWW + p4 + 1] = f2bf(xv.y);
        sXr[l * SWW + p4 + 2] = f2bf(xv.z); sXr[l * SWW + p4 + 3] = f2bf(xv.w);
        sXdT[(p4 + 0) * SWW + l] = f2bf(xv.x * d);
        sXdT[(p4 + 1) * SWW + l] = f2bf(xv.y * d);
        sXdT[(p4 + 2) * SWW + l] = f2bf(xv.z * d);
        sXdT[(p4 + 3) * SWW + l] = f2bf(xv.w * d);
    }
    __syncthreads();
    int fr = lane & 15, fk8 = (lane >> 4) * 8;
    int wr = wave >> 1, wc = wave & 1;
    fx4 g[2][2] = {};
    #pragma unroll
    for (int k = 0; k < 4; ++k) {
        bfx8 a0 = *(const bfx8*)&sC[(wr * 32 + fr) * SCW + k * 32 + fk8];
        bfx8 a1 = *(const bfx8*)&sC[(wr * 32 + 16 + fr) * SCW + k * 32 + fk8];
        bfx8 b0 = *(const bfx8*)&sB[(wc * 32 + fr) * SCW + k * 32 + fk8];
        bfx8 b1 = *(const bfx8*)&sB[(wc * 32 + 16 + fr) * SCW + k * 32 + fk8];
        g[0][0] = __builtin_amdgcn_mfma_f32_16x16x32_bf16(a0, b0, g[0][0], 0, 0, 0);
        g[0][1] = __builtin_amdgcn_mfma_f32_16x16x32_bf16(a0, b1, g[0][1], 0, 0, 0);
        g[1][0] = __builtin_amdgcn_mfma_f32_16x16x32_bf16(a1, b0, g[1][0], 0, 0, 0);
        g[1][1] = __builtin_amdgcn_mfma_f32_16x16x32_bf16(a1, b1, g[1][1], 0, 0, 0);
    }
    __syncthreads();
    int rb = wr * 32 + (lane >> 4) * 4;
    int cb = wc * 32 + fr;
    #pragma unroll
    for (int m = 0; m < 2; ++m)
        #pragma unroll
        for (int n = 0; n < 2; ++n)
            #pragma unroll
            for (int i = 0; i < 4; ++i) {
                int row = rb + m * 16 + i, col = cb + n * 16;
                float wv = (col <= row) ? g[m][n][i] * expf(sAcs[row] - sAcs[col]) : 0.f;
                sB[row * SWW + col] = f2bf(wv);
            }
    __syncthreads();
    fx4 yd[2][2] = {};
    fx4 sc[2][4] = {};
    #pragma unroll
    for (int k = 0; k < 2; ++k) {
        bfx8 aW0 = *(const bfx8*)&sB[(wr * 32 + fr) * SWW + k * 32 + fk8];
        bfx8 aW1 = *(const bfx8*)&sB[(wr * 32 + 16 + fr) * SWW + k * 32 + fk8];
        bfx8 bX0 = *(const bfx8*)&sXdT[(wc * 32 + fr) * SWW + k * 32 + fk8];
        bfx8 bX1 = *(const bfx8*)&sXdT[(wc * 32 + 16 + fr) * SWW + k * 32 + fk8];
        yd[0][0] = __builtin_amdgcn_mfma_f32_16x16x32_bf16(aW0, bX0, yd[0][0], 0, 0, 0);
        yd[0][1] = __builtin_amdgcn_mfma_f32_16x16x32_bf16(aW0, bX1, yd[0][1], 0, 0, 0);
        yd[1][0] = __builtin_amdgcn_mfma_f32_16x16x32_bf16(aW1, bX0, yd[1][0], 0, 0, 0);
        yd[1][1] = __builtin_amdgcn_mfma_f32_16x16x32_bf16(aW1, bX1, yd[1][1], 0, 0, 0);
        bfx8 aX0 = *(const bfx8*)&sXdT[(wr * 32 + fr) * SWW + k * 32 + fk8];
        bfx8 aX1 = *(const bfx8*)&sXdT[(wr * 32 + 16 + fr) * SWW + k * 32 + fk8];
        #pragma unroll
        for (int j = 0; j < 4; ++j) {
            bfx8 bB = *(const bfx8*)&sBdT[(wc * 64 + j * 16 + fr) * SWW + k * 32 + fk8];
            sc[0][j] = __builtin_amdgcn_mfma_f32_16x16x32_bf16(aX0, bB, sc[0][j], 0, 0, 0);
            sc[1][j] = __builtin_amdgcn_mfma_f32_16x16x32_bf16(aX1, bB, sc[1][j], 0, 0, 0);
        }
    }
    float Dh = Dp[h];
    #pragma unroll
    for (int m = 0; m < 2; ++m)
        #pragma unroll
        for (int i = 0; i < 4; ++i) {
            int row = rb + m * 16 + i;
            int tok = c * QC + row;
            if (tok < SEQL) {
                #pragma unroll
                for (int n = 0; n < 2; ++n) {
                    int col = cb + n * 16;
                    float xr = bf2f(sXr[row * SWW + col]);
                    ybuf[(size_t)(b * SEQL + tok) * DINNER + h * 64 + col] = yd[m][n][i] + Dh * xr;
                }
            }
        }
    #pragma unroll
    for (int m = 0; m < 2; ++m)
        #pragma unroll
        for (int i = 0; i < 4; ++i) {
            int p = rb + m * 16 + i;
            #pragma unroll
            for (int j = 0; j < 4; ++j) {
                int n = wc * 64 + j * 16 + fr;
                Sg[lin * 8192 + p * 128 + n] = sc[m][j][i];
            }
        }
}

__global__ __launch_bounds__(256) void k_scan2v(float* __restrict__ Sg,
                                                const float* __restrict__ cumA) {
    int bid = blockIdx.x;
    int bh = bid >> 5, sub = bid & 31;
    int e = sub * 256 + threadIdx.x;
    __shared__ float sT[NCH];
    if (threadIdx.x < NCH)
        sT[threadIdx.x] = cumA[((size_t)(bh * NCH) + threadIdx.x) * 64 + 63];
    __syncthreads();
    float S = 0.f;
    size_t base = (size_t)bh * NCH * 8192 + e;
    for (int g = 0; g < NCH; ++g) {
        size_t off = base + (size_t)g * 8192;
        float sg = Sg[off];
        Sg[off] = S;
        S = expf(sT[g]) * S + sg;
    }
}

__global__ __launch_bounds__(256) void k_yoff(const float* __restrict__ xbc,
                                              const float* __restrict__ Sg,
                                              const float* __restrict__ cumA,
                                              float* __restrict__ ybuf) {
    int bid = blockIdx.x;
    int h = bid & 31;
    int tmp = bid >> 5;
    int c = tmp & 15;
    int b = tmp >> 4;
    if (c == 0) return;
    size_t lin = (size_t)((b * NHEADS + h) * NCH + c);
    __shared__ unsigned short sC[64 * SCW];
    __shared__ unsigned short sS[64 * SCW];
    __shared__ float sE[64];
    int t = threadIdx.x;
    int lane = t & 63, wave = t >> 6;
    if (t < 64) sE[t] = expf(cumA[lin * 64 + t]);
    for (int i = t; i < 64 * 32; i += 256) {
        int l = i >> 5, n4 = (i & 31) * 4;
        int tok = c * QC + l;
        float4 cv = {0, 0, 0, 0};
        if (tok < SEQL)
            cv = *(const float4*)(xbc + (size_t)(b * SEQL + tok) * CONVDIM + DINNER + DSTATE + n4);
        sC[l * SCW + n4 + 0] = f2bf(cv.x); sC[l * SCW + n4 + 1] = f2bf(cv.y);
        sC[l * SCW + n4 + 2] = f2bf(cv.z); sC[l * SCW + n4 + 3] = f2bf(cv.w);
        float4 sv = *(const float4*)(Sg + lin * 8192 + l * 128 + n4);
        sS[l * SCW + n4 + 0] = f2bf(sv.x); sS[l * SCW + n4 + 1] = f2bf(sv.y);
        sS[l * SCW + n4 + 2] = f2bf(sv.z); sS[l * SCW + n4 + 3] = f2bf(sv.w);
    }
    __syncthreads();
    int fr = lane & 15, fk8 = (lane >> 4) * 8;
    int wr = wave >> 1, wc = wave & 1;
    fx4 yo[2][2] = {};
    #pragma unroll
    for (int k = 0; k < 4; ++k) {
        bfx8 a0 = *(const bfx8*)&sC[(wr * 32 + fr) * SCW + k * 32 + fk8];
        bfx8 a1 = *(const bfx8*)&sC[(wr * 32 + 16 + fr) * SCW + k * 32 + fk8];
        bfx8 b0 = *(const bfx8*)&sS[(wc * 32 + fr) * SCW + k * 32 + fk8];
        bfx8 b1 = *(const bfx8*)&sS[(wc * 32 + 16 + fr) * SCW + k * 32 + fk8];
        yo[0][0] = __builtin_amdgcn_mfma_f32_16x16x32_bf16(a0, b0, yo[0][0], 0, 0, 0);
        yo[0][1] = __builtin_amdgcn_mfma_f32_16x16x32_bf16(a0, b1, yo[0][1], 0, 0, 0);
        yo[1][0] = __builtin_amdgcn_mfma_f32_16x16x32_bf16(a1, b0, yo[1][0], 0, 0, 0);
        yo[1][1] = __builtin_amdgcn_mfma_f32_16x16x32_bf16(a1, b1, yo[1][1], 0, 0, 0);
    }
    int rb = wr * 32 + (lane >> 4) * 4;
    int cb = wc * 32 + fr;
    #pragma unroll
    for (int m = 0; m < 2; ++m)
        #pragma unroll
        for (int i = 0; i < 4; ++i) {
            int row = rb + m * 16 + i;
            int tok = c * QC + row;
            if (tok < SEQL) {
                float e = sE[row];
                #pragma unroll
                for (int n = 0; n < 2; ++n) {
                    int col = cb + n * 16;
                    size_t off = (size_t)(b * SEQL + tok) * DINNER + h * 64 + col;
                    ybuf[off] += yo[m][n][i] * e;
                }
            }
        }
}

// ---------------- gate (y * silu(z)) + RMSNorm + norm_w, output bf16 (padded) ----
__global__ __launch_bounds__(256) void k_norm(const float* __restrict__ ybuf,
                                              const float* __restrict__ zx,
                                              const float* __restrict__ normw,
                                              unsigned short* __restrict__ ynb) {
    int row = blockIdx.x;
    int t = threadIdx.x;
    if (row >= TOKENS) {
        #pragma unroll
        for (int j = 0; j < 8; ++j) ynb[(size_t)row * DINNER + t + j * 256] = 0;
        return;
    }
    float v[8];
    float ss = 0.f;
    #pragma unroll
    for (int j = 0; j < 8; ++j) {
        int col = t + j * 256;
        float y = ybuf[(size_t)row * DINNER + col];
        float z = zx[(size_t)row * NPROJ + col];
        y *= z / (1.f + expf(-z));
        v[j] = y;
        ss += y * y;
    }
    #pragma unroll
    for (int off = 32; off > 0; off >>= 1) ss += __shfl_down(ss, off, 64);
    __shared__ float red[4];
    int lane = t & 63, wv = t >> 6;
    if (lane == 0) red[wv] = ss;
    __syncthreads();
    float tot = red[0] + red[1] + red[2] + red[3];
    float r = rsqrtf(tot * (1.f / DINNER) + 1e-5f);
    #pragma unroll
    for (int j = 0; j < 8; ++j) {
        int col = t + j * 256;
        ynb[(size_t)row * DINNER + col] = f2bf(v[j] * r * normw[col]);
    }
}

extern "C" void kernel_launch(void* const* d_in, const int* in_sizes, int n_in,
                              void* d_out, int out_size, void* d_ws, size_t ws_size,
                              hipStream_t stream) {
    const float* x       = (const float*)d_in[0];
    const float* W_in    = (const float*)d_in[1];
    const float* conv_w  = (const float*)d_in[2];
    const float* conv_b  = (const float*)d_in[3];
    const float* dt_bias = (const float*)d_in[4];
    const float* A_log   = (const float*)d_in[5];
    const float* Dp      = (const float*)d_in[6];
    const float* norm_w  = (const float*)d_in[7];
    const float* W_out   = (const float*)d_in[8];
    float* out = (float*)d_out;

    char* w = (char*)d_ws;
    auto alloc = [&](size_t bytes) {
        char* p = w;
        w += (bytes + 255) & ~(size_t)255;
        return p;
    };
    unsigned short* xb    = (unsigned short*)alloc((size_t)MPAD * DMODEL * 2);
    unsigned short* winb  = (unsigned short*)alloc((size_t)NPAD1 * DMODEL * 2);
    unsigned short* woutb = (unsigned short*)alloc((size_t)DMODEL * DINNER * 2);
    float* zx   = (float*)alloc((size_t)TOKENS * NPROJ * 4);
    float* xbc  = (float*)alloc((size_t)TOKENS * CONVDIM * 4);
    float* dtv  = (float*)alloc((size_t)TOKENS * NHEADS * 4);
    float* yb   = (float*)alloc((size_t)TOKENS * DINNER * 4);
    unsigned short* ynb = (unsigned short*)alloc((size_t)MPAD * DINNER * 2);
    float* Sg   = (float*)alloc((size_t)BATCHN * NHEADS * NCH * HEADDIM * DSTATE * 4);
    float* cumA = (float*)alloc((size_t)BATCHN * NHEADS * NCH * 64 * 4);

    k_f2bf3<<<2048, 256, 0, stream>>>(x, W_in, W_out, xb, winb, woutb);
    k_dt<<<TOKENS / 8, 256, 0, stream>>>(x, W_in, dt_bias, dtv);
    // GEMM1: zx[2000][4384] = xb[2048][1024] * winb[4480][1024]^T, 1D grid 560 (35x16)
    k_gemmd<<<(NPAD1 / 128) * (MPAD / 128), 256, 0, stream>>>(
        xb, winb, zx, TOKENS, NPROJ, DMODEL, NPAD1 / 128);
    k_conv4<<<(TOKENS / 4) * CONVDIM / 256, 256, 0, stream>>>(zx, conv_w, conv_b, xbc);
    k_tile<<<BATCHN * NHEADS * NCH, 256, 0, stream>>>(xbc, dtv, A_log, Dp, yb, Sg, cumA);
    k_scan2v<<<BATCHN * NHEADS * 32, 256, 0, stream>>>(Sg, cumA);
    k_yoff<<<BATCHN * NHEADS * NCH, 256, 0, stream>>>(xbc, Sg, cumA, yb);
    k_norm<<<MPAD, 256, 0, stream>>>(yb, zx, norm_w, ynb);
    // GEMM2: out = ynb * woutb^T, 1D grid 256 (8x32), full-K, direct store
    k_gemmB<<<(DMODEL / 128) * (MPAD / 64), 256, 0, stream>>>(
        ynb, woutb, out, TOKENS, DMODEL, DINNER, DMODEL / 128);
}